// Round 13
// baseline (336.160 us; speedup 1.0000x reference)
//
#include <hip/hip_runtime.h>
#include <stdint.h>

// ---------------- types / helpers ----------------
typedef unsigned short bf16u;                                    // raw bf16 bits
typedef __attribute__((ext_vector_type(8))) __bf16 bf16x8;       // MFMA A/B frag
typedef __attribute__((ext_vector_type(4))) float f32x4;         // MFMA C/D frag
typedef __attribute__((ext_vector_type(4))) unsigned short u16x4;
typedef __attribute__((ext_vector_type(8))) unsigned short u16x8;

typedef __attribute__((address_space(1))) void gvoid_t;
typedef __attribute__((address_space(3))) void lvoid_t;

#define SEQ 2048
#define DM 1024
#define MN22 4194304   // 4096*1024
#define SCL 0.18033688f   // (1/8) * log2(e) — folded into Q at QKV epilogue

__device__ __forceinline__ bf16u f2bf(float f) {
  union { float f; uint32_t u; } v; v.f = f;
  uint32_t u = v.u + 0x7fffu + ((v.u >> 16) & 1u);   // RNE (finite values only)
  return (bf16u)(u >> 16);
}

// HW f32->bf16 (v_cvt class, RNE) — 1 op instead of 5-op bit twiddle.
__device__ __forceinline__ bf16u f2bf_hw(float f) {
  union { __bf16 h; bf16u u; } v; v.h = (__bf16)f; return v.u;
}

__device__ __forceinline__ float bf2f(bf16u b) {
  union { uint32_t u; float f; } v; v.u = (uint32_t)b << 16; return v.f;
}

// Raw v_exp_f32 (exp2). Plain exp2f without fast-math lowers to an OCML call
// with range/denormal fixup (~10 instrs) — this is 1 instr.
__device__ __forceinline__ float exp2_hw(float x) {
  return __builtin_amdgcn_exp2f(x);
}

// async global->LDS, 16 bytes per lane.
__device__ __forceinline__ void async_copy16(const bf16u* g, const bf16u* l) {
  __builtin_amdgcn_global_load_lds((gvoid_t*)(uintptr_t)g,
                                   (lvoid_t*)(uint32_t)(uintptr_t)l,
                                   16, 0, 0);
}

#define VM_WAIT(n) asm volatile("s_waitcnt vmcnt(" #n ")" ::: "memory")
#define LGKM0()    asm volatile("s_waitcnt lgkmcnt(0)" ::: "memory")
#define BARRIER()  asm volatile("s_barrier" ::: "memory")

// ---------------- LayerNorm (fp32 in -> bf16 out) ----------------
__global__ __launch_bounds__(256) void ln_kernel(const float* __restrict__ x,
                                                 const float* __restrict__ g,
                                                 const float* __restrict__ be,
                                                 bf16u* __restrict__ out) {
  const int row = blockIdx.x;
  const int t = threadIdx.x;
  const float4 v = ((const float4*)(x + (size_t)row * DM))[t];
  float s  = v.x + v.y + v.z + v.w;
  float ss = v.x * v.x + v.y * v.y + v.z * v.z + v.w * v.w;
#pragma unroll
  for (int m = 1; m < 64; m <<= 1) {
    s  += __shfl_xor(s, m, 64);
    ss += __shfl_xor(ss, m, 64);
  }
  __shared__ float red[2][4];
  const int wv = t >> 6, ln = t & 63;
  if (ln == 0) { red[0][wv] = s; red[1][wv] = ss; }
  __syncthreads();
  s  = red[0][0] + red[0][1] + red[0][2] + red[0][3];
  ss = red[1][0] + red[1][1] + red[1][2] + red[1][3];
  const float mu = s * (1.0f / DM);
  const float var = ss * (1.0f / DM) - mu * mu;
  const float rstd = rsqrtf(var + 1e-5f);
  const float4 gg = ((const float4*)g)[t];
  const float4 bb = ((const float4*)be)[t];
  u16x4 o;
  o[0] = f2bf((v.x - mu) * rstd * gg.x + bb.x);
  o[1] = f2bf((v.y - mu) * rstd * gg.y + bb.y);
  o[2] = f2bf((v.z - mu) * rstd * gg.z + bb.z);
  o[3] = f2bf((v.w - mu) * rstd * gg.w + bb.w);
  *(u16x4*)(out + (size_t)row * DM + t * 4) = o;
}

// ---------------- fused preprocessing: LN1 + all weight transposes ----------
// blocks 0..4095: LN rows | 4096..8191: wq/wk/wv/wo 32x32 tiles |
// 8192..12287: w1 (1024x4096) | 12288..16383: w2 (4096x1024).
__global__ __launch_bounds__(256) void prep_kernel(
    const float* __restrict__ x, const float* __restrict__ g,
    const float* __restrict__ be, bf16u* __restrict__ lnout,
    const float* __restrict__ wq, const float* __restrict__ wk,
    const float* __restrict__ wv_, const float* __restrict__ wo,
    bf16u* __restrict__ wqkv_t,
    const float* __restrict__ w1, bf16u* __restrict__ w1_t,
    const float* __restrict__ w2, bf16u* __restrict__ w2_t) {
  const int bid = blockIdx.x;
  const int t = threadIdx.x;
  if (bid < 4096) {
    const int row = bid;
    const float4 v = ((const float4*)(x + (size_t)row * DM))[t];
    float s  = v.x + v.y + v.z + v.w;
    float ss = v.x * v.x + v.y * v.y + v.z * v.z + v.w * v.w;
#pragma unroll
    for (int m = 1; m < 64; m <<= 1) {
      s  += __shfl_xor(s, m, 64);
      ss += __shfl_xor(ss, m, 64);
    }
    __shared__ float red[2][4];
    const int wv = t >> 6, ln = t & 63;
    if (ln == 0) { red[0][wv] = s; red[1][wv] = ss; }
    __syncthreads();
    s  = red[0][0] + red[0][1] + red[0][2] + red[0][3];
    ss = red[1][0] + red[1][1] + red[1][2] + red[1][3];
    const float mu = s * (1.0f / DM);
    const float var = ss * (1.0f / DM) - mu * mu;
    const float rstd = rsqrtf(var + 1e-5f);
    const float4 gg = ((const float4*)g)[t];
    const float4 bb = ((const float4*)be)[t];
    u16x4 o;
    o[0] = f2bf((v.x - mu) * rstd * gg.x + bb.x);
    o[1] = f2bf((v.y - mu) * rstd * gg.y + bb.y);
    o[2] = f2bf((v.z - mu) * rstd * gg.z + bb.z);
    o[3] = f2bf((v.w - mu) * rstd * gg.w + bb.w);
    *(u16x4*)(lnout + (size_t)row * DM + t * 4) = o;
    return;
  }
  __shared__ float tile[32][33];
  const int tx = t & 31, ty = t >> 5;
  const float* in; bf16u* o; int R, C, c0, r0;
  if (bid < 8192) {
    const int idx = bid - 4096;
    const int mat = idx >> 10, rem = idx & 1023;
    const float* srcs[4] = {wq, wk, wv_, wo};
    in = srcs[mat]; o = wqkv_t + (size_t)mat * 1024 * 1024;   // wo lands at wo_t
    R = 1024; C = 1024;
    c0 = (rem & 31) * 32; r0 = (rem >> 5) * 32;
  } else if (bid < 12288) {
    const int idx = bid - 8192;
    in = w1; o = w1_t; R = 1024; C = 4096;
    c0 = (idx & 127) * 32; r0 = (idx >> 7) * 32;
  } else {
    const int idx = bid - 12288;
    in = w2; o = w2_t; R = 4096; C = 1024;
    c0 = (idx & 31) * 32; r0 = (idx >> 5) * 32;
  }
#pragma unroll
  for (int i = 0; i < 4; ++i)
    tile[ty + i * 8][tx] = in[(size_t)(r0 + ty + i * 8) * C + c0 + tx];
  __syncthreads();
#pragma unroll
  for (int i = 0; i < 4; ++i)
    o[(size_t)(c0 + ty + i * 8) * R + r0 + tx] = f2bf(tile[tx][ty + i * 8]);
}

// ---------------- split-K combine: out += p0 + p1 + p2 + bias ----------------
__global__ __launch_bounds__(256) void reduce3(const bf16u* __restrict__ p01,
                                               const bf16u* __restrict__ p2,
                                               const float* __restrict__ bias,
                                               float* __restrict__ out) {
  const size_t i8 = ((size_t)blockIdx.x * 256 + threadIdx.x) * 8;
  const int col0 = (int)(i8 & 1023);
  const u16x8 a = *(const u16x8*)(p01 + i8);
  const u16x8 b = *(const u16x8*)(p01 + MN22 + i8);
  const u16x8 c = *(const u16x8*)(p2 + i8);
  const float4 o0 = *(const float4*)(out + i8);
  const float4 o1 = *(const float4*)(out + i8 + 4);
  const float4 b0 = *(const float4*)(bias + col0);
  const float4 b1 = *(const float4*)(bias + col0 + 4);
  float r[8];
#pragma unroll
  for (int j = 0; j < 8; ++j) r[j] = bf2f(a[j]) + bf2f(b[j]) + bf2f(c[j]);
  float4 w0, w1;
  w0.x = o0.x + r[0] + b0.x; w0.y = o0.y + r[1] + b0.y;
  w0.z = o0.z + r[2] + b0.z; w0.w = o0.w + r[3] + b0.w;
  w1.x = o1.x + r[4] + b1.x; w1.y = o1.y + r[5] + b1.y;
  w1.z = o1.z + r[6] + b1.z; w1.w = o1.w + r[7] + b1.w;
  *(float4*)(out + i8) = w0;
  *(float4*)(out + i8 + 4) = w1;
}

// ---------------- GEMM 128x128, BK=64, 2-phase pipelined, 512 thr ----------
// 8 waves (2M x 4N), per-wave C = 64x32 => acc[4][2] f32x4 (32 VGPR).
// LDS 64 KiB: 2 bufs x (A 128x64 + B 128x64) => 2 blocks/CU = 32 waves/CU.
// Quarter row-permutation (proven in R12): quarter q holds global rows
// (lr&31) + (lr>>5)*64 + q*32. Phase h computes per-wave rows
// wm*64 + h*32 + [0,32) — entirely within Aq(h) for EVERY wave. B frags
// (cols wn*32+[0,32)) live in Bq(wn&1), read in phase 1, reused in phase 2.
// Stage order per tile: Bq0,Bq1,Aq0,Aq1 (1 load/thread each). Steady-state
// in-flight = {Aq1}: ph1 stages Bq0n, VM_WAIT(1) retires Aq1(cur); ph2
// stages Bq1n+Aq0n, MFMA, stages Aq1n, VM_WAIT(1) retires the 3 older.
// 16B slots XOR-swizzled by row&7 (conflict-free ds_read_b128).
// mode 0: bf16 | 1: +bias,relu,bf16 | 5: QKV fused (Q pre-scale n0<1024,
// V^T emit n0>=2048) | 6: split-K=3 bf16 partials (combined by reduce3).
__global__ __launch_bounds__(512, 4) void gemm256(
    const bf16u* __restrict__ A, const bf16u* __restrict__ Bt,
    int M, int N, int K,
    const float* __restrict__ bias, bf16u* __restrict__ outB,
    bf16u* __restrict__ vt, int mode) {
  __shared__ bf16u sh[2][16384];
  const int t = threadIdx.x;
  const int ln = t & 63;
  const int wv = t >> 6;
  const int col16 = ln & 15, quad = ln >> 4;
  const int wm = wv >> 2, wn = wv & 3;    // 2M x 4N

  // T1: XCD-aware swizzle of the 1-D grid (nwg % 8 == 0 for our shapes)
  const int nsplit = (mode == 6) ? 3 : 1;
  const int nbx = N >> 7;
  const int nwg = nbx * (M >> 7) * nsplit;
  const int cpx = nwg >> 3;
  const int bid = blockIdx.x;
  const int swz = (bid & 7) * cpx + (bid >> 3);
  const int tile = swz / nsplit, split = swz - tile * nsplit;
  const int m0 = (tile / nbx) << 7, n0 = (tile % nbx) << 7;
  // K-range of this split (in BK=64 steps)
  const int tsteps = K >> 6;
  const int kbeg = (split * tsteps) / nsplit;
  const int nt = ((split + 1) * tsteps) / nsplit - kbeg;
  const size_t koff = (size_t)kbeg << 6;

  // staging: 1 chunk (16B) per thread per quarter; lr = t>>3 in [0,64).
  const int lr = t >> 3, slot = (t & 7) ^ (lr & 7);
  const int rq = (lr & 31) + ((lr >> 5) << 6);   // quarter row permutation
  // stage index s: 0=Bq0, 1=Bq1, 2=Aq0, 3=Aq1
  const bf16u* gsrc[4];
  gsrc[0] = Bt + (size_t)(n0 + rq) * K + koff + slot * 8;
  gsrc[1] = Bt + (size_t)(n0 + rq + 32) * K + koff + slot * 8;
  gsrc[2] = A  + (size_t)(m0 + rq) * K + koff + slot * 8;
  gsrc[3] = A  + (size_t)(m0 + rq + 32) * K + koff + slot * 8;
  int doff[4];
  doff[0] = 8192  + t * 8;   // Bq0
  doff[1] = 12288 + t * 8;   // Bq1
  doff[2] = 0     + t * 8;   // Aq0
  doff[3] = 4096  + t * 8;   // Aq1

  // ds_read offsets; row r: quarter (r>>5)&1, lds row (r&31)+(r>>6)*32.
  int aoffs[2][2][2], boffs[2][2];   // aoffs[h][i][kc], boffs[i][kc]
#pragma unroll
  for (int h = 0; h < 2; ++h)
#pragma unroll
    for (int i = 0; i < 2; ++i)
#pragma unroll
      for (int kc = 0; kc < 2; ++kc) {
        const int ra = wm * 64 + h * 32 + i * 16 + col16;
        const int la = ((ra >> 5) & 1) * 4096 + (((ra & 31) + ((ra >> 6) << 5)) << 6);
        aoffs[h][i][kc] = la + (((kc << 2) + quad) ^ (ra & 7)) * 8;
      }
#pragma unroll
  for (int i = 0; i < 2; ++i)
#pragma unroll
    for (int kc = 0; kc < 2; ++kc) {
      const int rb = wn * 32 + i * 16 + col16;
      const int lb = ((rb >> 5) & 1) * 4096 + (((rb & 31) + ((rb >> 6) << 5)) << 6);
      boffs[i][kc] = 8192 + lb + (((kc << 2) + quad) ^ (rb & 7)) * 8;
    }

  f32x4 acc[4][2] = {};              // [m-frag 0..3][n-frag 0..1]
  bf16x8 Af[2][2], Bf[2][2];

  auto stage = [&](int s, int b) {
    async_copy16(gsrc[s], &sh[b][doff[s]]);
    gsrc[s] += 64;
  };
  auto readA = [&](int b, int h) {
#pragma unroll
    for (int i = 0; i < 2; ++i)
#pragma unroll
      for (int kc = 0; kc < 2; ++kc)
        Af[i][kc] = *(const bf16x8*)(&sh[b][aoffs[h][i][kc]]);
  };
  auto readB = [&](int b) {
#pragma unroll
    for (int i = 0; i < 2; ++i)
#pragma unroll
      for (int kc = 0; kc < 2; ++kc)
        Bf[i][kc] = *(const bf16x8*)(&sh[b][boffs[i][kc]]);
  };
  auto mfmaH = [&](int h) {
#pragma unroll
    for (int kc = 0; kc < 2; ++kc)
#pragma unroll
      for (int mi = 0; mi < 2; ++mi)
#pragma unroll
        for (int ni = 0; ni < 2; ++ni)
          acc[h * 2 + mi][ni] = __builtin_amdgcn_mfma_f32_16x16x32_bf16(
              Af[mi][kc], Bf[ni][kc], acc[h * 2 + mi][ni], 0, 0, 0);
  };

  // prologue: tile 0 into buf 0; Bq0,Bq1,Aq0 landed, Aq1 in flight.
  stage(0, 0); stage(1, 0); stage(2, 0); stage(3, 0);
  VM_WAIT(1);
  BARRIER();

  int bsel = 0;
  for (int kt = 0; kt < nt; ++kt, bsel ^= 1) {
    const int bn = bsel ^ 1;
    const bool more = (kt + 1 < nt);
    // ---- phase 1 (h=0): needs Bq0+Bq1+Aq0 (all landed) ----
    readB(bsel); readA(bsel, 0);
    if (more) stage(0, bn);            // Bq0 next
    BARRIER(); LGKM0();
    __builtin_amdgcn_s_setprio(1); mfmaH(0); __builtin_amdgcn_s_setprio(0);
    if (more) { VM_WAIT(1); } else { VM_WAIT(0); }   // retire Aq1(cur)
    BARRIER();
    // ---- phase 2 (h=1): needs Aq1 (just retired) ----
    readA(bsel, 1);
    if (more) { stage(1, bn); stage(2, bn); }        // Bq1,Aq0 next
    BARRIER(); LGKM0();
    __builtin_amdgcn_s_setprio(1); mfmaH(1); __builtin_amdgcn_s_setprio(0);
    if (more) {
      stage(3, bn);                                  // Aq1 next
      VM_WAIT(1);                                    // retire Bq0n,Bq1n,Aq0n
    }
    BARRIER();
  }

  // ---- epilogue ----
  if (mode == 6) {
    bf16u* pb = (split < 2) ? outB + (size_t)split * MN22 : vt;
#pragma unroll
    for (int mi = 0; mi < 4; ++mi) {
#pragma unroll
      for (int n = 0; n < 2; ++n) {
        const int col = n0 + wn * 32 + n * 16 + col16;
#pragma unroll
        for (int r = 0; r < 4; ++r) {
          const int row = m0 + wm * 64 + mi * 16 + quad * 4 + r;
          pb[(size_t)row * N + col] = f2bf(acc[mi][n][r]);
        }
      }
    }
    return;
  }
  if (mode == 5 && n0 >= 2048) {
    // fused vtrans: V section -> vt[(b*16+h)*64 + d][s], packed 8B stores.
#pragma unroll
    for (int mi = 0; mi < 4; ++mi) {
#pragma unroll
      for (int n = 0; n < 2; ++n) {
        const int col = n0 + wn * 32 + n * 16 + col16;
        const int hh = (col - 2048) >> 6, d = (col - 2048) & 63;
        const int row_base = m0 + wm * 64 + mi * 16 + quad * 4;
        const int bb = row_base >> 11, s = row_base & 2047;
        u16x4 o;
#pragma unroll
        for (int r = 0; r < 4; ++r) o[r] = f2bf(acc[mi][n][r]);
        *(u16x4*)(vt + (size_t)((bb * 16 + hh) * 64 + d) * SEQ + s) = o;
      }
    }
    return;
  }
  // Q pre-scale: fold softmax 1/sqrt(d)*log2(e) into the Q section of QKV.
  const float qscale = (mode == 5 && n0 < 1024) ? SCL : 1.0f;
  float bv[2];
  if (mode == 1) {
#pragma unroll
    for (int n = 0; n < 2; ++n) bv[n] = bias[n0 + wn * 32 + n * 16 + col16];
  }
#pragma unroll
  for (int mi = 0; mi < 4; ++mi) {
#pragma unroll
    for (int n = 0; n < 2; ++n) {
      const int col = n0 + wn * 32 + n * 16 + col16;
#pragma unroll
      for (int r = 0; r < 4; ++r) {
        const int row = m0 + wm * 64 + mi * 16 + quad * 4 + r;
        float v = acc[mi][n][r];
        if (mode == 1) v = fmaxf(v + bv[n], 0.0f);
        outB[(size_t)row * N + col] = f2bf(v * qscale);
      }
    }
  }
}

// ---------------- GEMM 64x128, BK=64, swizzled LDS, pipelined (wo GEMM) -----
// mode 2: +resid fp32 | 3: +bias+resid fp32
__global__ __launch_bounds__(256, 3) void gemm_bt64(
    const bf16u* __restrict__ A, const bf16u* __restrict__ Bt,
    int M, int N, int K,
    const float* __restrict__ bias, const float* __restrict__ resid,
    bf16u* __restrict__ outB, float* __restrict__ outF, int mode) {
  __shared__ bf16u As0[64 * 64], As1[64 * 64];
  __shared__ bf16u Bs0[128 * 64], Bs1[128 * 64];
  const int t = threadIdx.x;
  const int ln = t & 63;
  const int wv = t >> 6;
  const int col16 = ln & 15, quad = ln >> 4;

  const int nbx = gridDim.x;
  const int nwg = nbx * gridDim.y;          // 512 for our launches (%8==0)
  const int cpx = nwg >> 3;
  const int flat = blockIdx.y * nbx + blockIdx.x;
  const int swz = (flat & 7) * cpx + (flat >> 3);
  const int m0 = (swz / nbx) * 64, n0 = (swz % nbx) * 128;

  const bf16u* gA[2];
  const bf16u* gB[4];
#pragma unroll
  for (int j = 0; j < 2; ++j) {
    const int c = t + 256 * j, row = c >> 3, slot = (c & 7) ^ (row & 7);
    gA[j] = A + (size_t)(m0 + row) * K + slot * 8;
  }
#pragma unroll
  for (int j = 0; j < 4; ++j) {
    const int c = t + 256 * j, row = c >> 3, slot = (c & 7) ^ (row & 7);
    gB[j] = Bt + (size_t)(n0 + row) * K + slot * 8;
  }

  f32x4 acc[4][2] = {};

  auto stage = [&](bf16u* dA, bf16u* dB) {
#pragma unroll
    for (int j = 0; j < 2; ++j) {
      async_copy16(gA[j], dA + (size_t)(t + 256 * j) * 8);
      gA[j] += 64;
    }
#pragma unroll
    for (int j = 0; j < 4; ++j) {
      async_copy16(gB[j], dB + (size_t)(t + 256 * j) * 8);
      gB[j] += 64;
    }
  };
  auto compute = [&](const bf16u* sA, const bf16u* sB) {
    bf16x8 af[4][2], bfv[2][2];
#pragma unroll
    for (int mi = 0; mi < 4; ++mi) {
      const int row = mi * 16 + col16;
#pragma unroll
      for (int kc = 0; kc < 2; ++kc)
        af[mi][kc] = *(const bf16x8*)(sA + row * 64 + (((kc << 2) + quad) ^ (row & 7)) * 8);
    }
#pragma unroll
    for (int ni = 0; ni < 2; ++ni) {
      const int row = wv * 32 + ni * 16 + col16;
#pragma unroll
      for (int kc = 0; kc < 2; ++kc)
        bfv[ni][kc] = *(const bf16x8*)(sB + row * 64 + (((kc << 2) + quad) ^ (row & 7)) * 8);
    }
#pragma unroll
    for (int kc = 0; kc < 2; ++kc)
#pragma unroll
      for (int mi = 0; mi < 4; ++mi)
#pragma unroll
        for (int ni = 0; ni < 2; ++ni)
          acc[mi][ni] = __builtin_amdgcn_mfma_f32_16x16x32_bf16(af[mi][kc], bfv[ni][kc],
                                                                acc[mi][ni], 0, 0, 0);
  };

  const int niter = K >> 6;     // 16 (wo) — even
  stage(As0, Bs0);
  for (int k = 0; k < niter; k += 2) {
    stage(As1, Bs1);
    VM_WAIT(6);
    BARRIER();
    compute(As0, Bs0);
    BARRIER();
    if (k + 2 < niter) {
      stage(As0, Bs0);
      VM_WAIT(6);
    } else {
      VM_WAIT(0);
    }
    BARRIER();
    compute(As1, Bs1);
    BARRIER();
  }

#pragma unroll
  for (int mi = 0; mi < 4; ++mi) {
#pragma unroll
    for (int ni = 0; ni < 2; ++ni) {
      const int col = n0 + wv * 32 + ni * 16 + col16;
#pragma unroll
      for (int r = 0; r < 4; ++r) {
        const int row = m0 + mi * 16 + quad * 4 + r;
        float v = acc[mi][ni][r];
        if (mode == 1 || mode == 3) v += bias[col];
        if (mode == 1) v = fmaxf(v, 0.0f);
        if (mode >= 2) {
          outF[(size_t)row * N + col] = v + resid[(size_t)row * N + col];
        } else {
          outB[(size_t)row * N + col] = f2bf(v);
        }
      }
    }
  }
}

// ---------------- causal flash attention v6 + raw v_exp_f32 + setprio -------
// One 64-q-row strip per block, grid (bh=32, strips=32) heavy-first.
// Q pre-scaled by SCL at QKV epilogue. Softmax exp2 via v_exp_f32.
// Rotated software pipeline with RAW barriers + counted vmcnt.
// PV uses swapped MFMA operands -> O^T in C layout -> packed u16x4 stores.
#define PST 132   // pbuf row stride (elements): 128 keys + 4 pad
__global__ __launch_bounds__(256, 3) void attn_kernel(const bf16u* __restrict__ qkv,
                                                      const bf16u* __restrict__ vt,
                                                      bf16u* __restrict__ out) {
  __shared__ bf16u Ks[128 * 64];
  __shared__ bf16u Vts[2 * 64 * 64];
  __shared__ bf16u pbuf[4][16 * PST];
  __shared__ float lred[4][16];
  const int t = threadIdx.x;
  const int wv = t >> 6, ln = t & 63;
  const int col = ln & 15, quad = ln >> 4;
  const int bh = blockIdx.x, b = bh >> 4, h = bh & 15;
  const int strip = 31 - blockIdx.y;       // heavy blocks dispatch first
  const int q0 = strip * 64;
  const int qw = q0 + wv * 16;
  const int qmax = qw + 15;
  const int ntiles = (q0 >> 7) + 1;

  int krow[4], kslot[4], vrow[4], vsub[4], vslot[4];
  const bf16u *kl[4], *vl[4];
#pragma unroll
  for (int j = 0; j < 4; ++j) {
    const int c = t + 256 * j;
    krow[j] = c >> 3; kslot[j] = (c & 7) ^ (krow[j] & 7);
    const int rem = c & 511;
    vsub[j] = c >> 9; vrow[j] = rem >> 3; vslot[j] = (rem & 7) ^ (vrow[j] & 7);
    kl[j] = Ks + (size_t)c * 8;
    vl[j] = Vts + (size_t)c * 8;
  }

  auto stageK = [&](int kb) {
    const int kbase = kb * 128;
#pragma unroll
    for (int j = 0; j < 4; ++j)
      async_copy16(qkv + (size_t)(b * SEQ + kbase + krow[j]) * 3072 + 1024 + h * 64 + kslot[j] * 8, kl[j]);
  };
  auto stageV = [&](int kb) {
    const int kbase = kb * 128;
#pragma unroll
    for (int j = 0; j < 4; ++j)
      async_copy16(vt + (size_t)(bh * 64 + vrow[j]) * SEQ + kbase + vsub[j] * 64 + vslot[j] * 8, vl[j]);
  };

  bf16x8 qf0, qf1;
  {
    const size_t qoff = (size_t)(b * SEQ + qw + col) * 3072 + h * 64 + quad * 8;
    qf0 = *(const bf16x8*)(qkv + qoff);
    qf1 = *(const bf16x8*)(qkv + qoff + 32);
  }
  f32x4 po[4] = {};          // O^T accum: po[n] rows hd=n*16+quad*4+r, col q
  float ll[4] = {};          // per-lane softmax denominator partials

  stageK(0);
  stageV(0);
  VM_WAIT(4);                // K0 landed (+ Q regs); V0 stays in flight
  BARRIER();

  for (int kb = 0; kb < ntiles; ++kb) {
    const int kbase = kb * 128;
    if (kb < ntiles - 1) {
      // ---------- fully-unmasked 128-key tile ----------
      f32x4 sc[8];
      __builtin_amdgcn_s_setprio(1);
#pragma unroll
      for (int n = 0; n < 8; ++n) {
        const int kr = n * 16 + col;
        const bf16x8 k0 = *(const bf16x8*)(Ks + kr * 64 + (quad ^ (kr & 7)) * 8);
        const bf16x8 k1 = *(const bf16x8*)(Ks + kr * 64 + ((4 + quad) ^ (kr & 7)) * 8);
        f32x4 z = {};
        z = __builtin_amdgcn_mfma_f32_16x16x32_bf16(qf0, k0, z, 0, 0, 0);
        sc[n] = __builtin_amdgcn_mfma_f32_16x16x32_bf16(qf1, k1, z, 0, 0, 0);
      }
      __builtin_amdgcn_s_setprio(0);
#pragma unroll
      for (int r = 0; r < 4; ++r) {
#pragma unroll
        for (int n = 0; n < 8; ++n) {
          const float e = exp2_hw(sc[n][r]);
          ll[r] += e;
          pbuf[wv][(quad * 4 + r) * PST + n * 16 + col] = f2bf_hw(e);
        }
      }
    } else {
      // ---------- diagonal tile: mask + wave-uniform n-tile skip ----------
      f32x4 sc[8];
      bool act[8];
      __builtin_amdgcn_s_setprio(1);
#pragma unroll
      for (int n = 0; n < 8; ++n) {
        act[n] = (kbase + n * 16) <= qmax;
        if (act[n]) {
          const int kr = n * 16 + col;
          const bf16x8 k0 = *(const bf16x8*)(Ks + kr * 64 + (quad ^ (kr & 7)) * 8);
          const bf16x8 k1 = *(const bf16x8*)(Ks + kr * 64 + ((4 + quad) ^ (kr & 7)) * 8);
          f32x4 z = {};
          z = __builtin_amdgcn_mfma_f32_16x16x32_bf16(qf0, k0, z, 0, 0, 0);
          sc[n] = __builtin_amdgcn_mfma_f32_16x16x32_bf16(qf1, k1, z, 0, 0, 0);
        }
      }
      __builtin_amdgcn_s_setprio(0);
#pragma unroll
      for (int r = 0; r < 4; ++r) {
        const int q = qw + quad * 4 + r;
#pragma unroll
        for (int n = 0; n < 8; ++n) {
          float e = 0.0f;
          if (act[n]) {
            float v = sc[n][r];
            v = (kbase + n * 16 + col <= q) ? v : -1e30f;   // v_exp_f32 -> 0
            e = exp2_hw(v);
          }
          ll[r] += e;
          pbuf[wv][(quad * 4 + r) * PST + n * 16 + col] = f2bf_hw(e);
        }
      }
    }
    LGKM0();           // wave-local P writes done (drains Ks reads too)
    bf16x8 pa[4];
#pragma unroll
    for (int kc = 0; kc < 4; ++kc)
      pa[kc] = *(const bf16x8*)(&pbuf[wv][col * PST + kc * 32 + quad * 8]);
    VM_WAIT(0);        // V_kb landed
    BARRIER();         // all waves: Ks reads drained, Vts populated
    if (kb + 1 < ntiles) stageK(kb + 1);   // K latency hides under PV
    if (kb < ntiles - 1) {
      __builtin_amdgcn_s_setprio(1);
#pragma unroll
      for (int n = 0; n < 4; ++n) {
        const int vr = n * 16 + col;
#pragma unroll
        for (int kc = 0; kc < 4; ++kc) {
          const bf16x8 vfr = *(const bf16x8*)(Vts + (kc >> 1) * 4096 + vr * 64 +
                                              (((kc & 1) * 4 + quad) ^ (vr & 7)) * 8);
          // swapped operands: C = V^T * P^T = O^T (col=q, row=hd)
          po[n] = __builtin_amdgcn_mfma_f32_16x16x32_bf16(vfr, pa[kc], po[n], 0, 0, 0);
        }
      }
      __builtin_amdgcn_s_setprio(0);
    } else {
      __builtin_amdgcn_s_setprio(1);
#pragma unroll
      for (int n = 0; n < 4; ++n) {
        const int vr = n * 16 + col;
#pragma unroll
        for (int kc = 0; kc < 4; ++kc)
          if (kbase + kc * 32 <= qmax) {
            const bf16x8 vfr = *(const bf16x8*)(Vts + (kc >> 1) * 4096 + vr * 64 +
                                                (((kc & 1) * 4 + quad) ^ (vr & 7)) * 8);
            po[n] = __builtin_amdgcn_mfma_f32_16x16x32_bf16(vfr, pa[kc], po[n], 0, 0, 0);
          }
      }
      __builtin_amdgcn_s_setprio(0);
    }
    if (kb + 1 < ntiles) {
      LGKM0();         // own Vts reads drained
      BARRIER();       // all waves done reading Vts
      stageV(kb + 1);  // V latency hides under next QK^T+softmax
      VM_WAIT(4);      // K_{kb+1} landed (in-order retire); V in flight
      BARRIER();
    }
  }

  // reduce l across the 16 q-columns, broadcast via LDS, normalize, store O^T
#pragma unroll
  for (int m = 1; m < 16; m <<= 1)
#pragma unroll
    for (int r = 0; r < 4; ++r) ll[r] += __shfl_xor(ll[r], m, 64);
  if (col == 0) {
#pragma unroll
    for (int r = 0; r < 4; ++r) lred[wv][quad * 4 + r] = ll[r];
  }
  LGKM0();
  const float inv = 1.0f / lred[wv][col];
#pragma unroll
  for (int n = 0; n < 4; ++n) {
    u16x4 o;
#pragma unroll
    for (int r = 0; r < 4; ++r) o[r] = f2bf(po[n][r] * inv);
    *(u16x4*)(out + (size_t)(b * SEQ + qw + col) * DM + h * 64 + n * 16 + quad * 4) = o;
  }
}

// ---------------- launch ----------------
extern "C" void kernel_launch(void* const* d_in, const int* in_sizes, int n_in,
                              void* d_out, int out_size, void* d_ws, size_t ws_size,
                              hipStream_t stream) {
  const float* x   = (const float*)d_in[0];
  const float* wq  = (const float*)d_in[1];
  const float* wk  = (const float*)d_in[2];
  const float* wvv = (const float*)d_in[3];
  const float* wo  = (const float*)d_in[4];
  const float* w1  = (const float*)d_in[5];
  const float* b1  = (const float*)d_in[6];
  const float* w2  = (const float*)d_in[7];
  const float* b2  = (const float*)d_in[8];
  const float* g1  = (const float*)d_in[9];
  const float* be1 = (const float*)d_in[10];
  const float* g2  = (const float*)d_in[11];
  const float* be2 = (const float*)d_in[12];
  float* out = (float*)d_out;

  char* ws = (char*)d_ws;
  bf16u* wqkv_t = (bf16u*)(ws);              //  0 ..  6 MB  (3072 x 1024)
  bf16u* wo_t   = (bf16u*)(ws +  6291456);   //  6 ..  8 MB  (1024 x 1024)
  bf16u* w1_t   = (bf16u*)(ws +  8388608);   //  8 .. 16 MB  (4096 x 1024)
  bf16u* w2_t   = (bf16u*)(ws + 16777216);   // 16 .. 24 MB  (1024 x 4096)
  bf16u* lnbuf  = (bf16u*)(ws + 25165824);   // 24 .. 32 MB  (4096 x 1024) also attn out
  bf16u* qkv    = (bf16u*)(ws + 33554432);   // 32 .. 56 MB  (4096 x 3072)
  bf16u* vtb    = (bf16u*)(ws + 58720256);   // 56 .. 64 MB  (32 x 64 x 2048)
  bf16u* h1     = (bf16u*)(ws + 33554432);   // 32 .. 64 MB  (reuse: 4096 x 4096)
  bf16u* attn   = lnbuf;                     // ln1 dead after QKV GEMM
  // FFN2 split-K partials (bf16, 8 MB each) in regions dead at FFN2 time:
  bf16u* p01 = (bf16u*)(ws);                 //  0 .. 16 MB (over dead wqkv/wo/w1)
  bf16u* p2  = (bf16u*)(ws + 25165824);      // 24 .. 32 MB (over dead lnbuf)

  // fused preprocessing: LN1 + all weight transposes in ONE launch
  prep_kernel<<<16384, 256, 0, stream>>>(x, g1, be1, lnbuf,
                                         wq, wk, wvv, wo, wqkv_t,
                                         w1, w1_t, w2, w2_t);
  // QKV with fused V-transpose + Q pre-scale (mode 5). 128x128 tiles.
  gemm256<<<768, 512, 0, stream>>>(lnbuf, wqkv_t, 4096, 3072, 1024,
                                   nullptr, qkv, vtb, 5);
  attn_kernel<<<dim3(32, 32), 256, 0, stream>>>(qkv, vtb, attn);
  gemm_bt64<<<dim3(8, 64), 256, 0, stream>>>(attn, wo_t, 4096, 1024, 1024,
                                             nullptr, x, nullptr, out, 2);
  ln_kernel<<<4096, 256, 0, stream>>>(out, g2, be2, lnbuf);
  gemm256<<<1024, 512, 0, stream>>>(lnbuf, w1_t, 4096, 4096, 1024,
                                    b1, h1, nullptr, 1);
  // FFN2: split-K=3 (768 blocks of the 128x128 pipeline), bf16 partials to
  // dead ws regions, then combined with bias into out (holds attn@wo + x).
  gemm256<<<768, 512, 0, stream>>>(h1, w2_t, 4096, 1024, 4096,
                                   nullptr, p01, p2, 6);
  reduce3<<<2048, 256, 0, stream>>>(p01, p2, b2, out);
}

// Round 14
// 324.226 us; speedup vs baseline: 1.0368x; 1.0368x over previous
//
#include <hip/hip_runtime.h>
#include <stdint.h>

// ---------------- types / helpers ----------------
typedef unsigned short bf16u;                                    // raw bf16 bits
typedef __attribute__((ext_vector_type(8))) __bf16 bf16x8;       // MFMA A/B frag
typedef __attribute__((ext_vector_type(4))) float f32x4;         // MFMA C/D frag
typedef __attribute__((ext_vector_type(4))) unsigned short u16x4;
typedef __attribute__((ext_vector_type(8))) unsigned short u16x8;

typedef __attribute__((address_space(1))) void gvoid_t;
typedef __attribute__((address_space(3))) void lvoid_t;

#define SEQ 2048
#define DM 1024
#define MN22 4194304   // 4096*1024
#define SCL 0.18033688f   // (1/8) * log2(e) — folded into Q at QKV epilogue

__device__ __forceinline__ bf16u f2bf(float f) {
  union { float f; uint32_t u; } v; v.f = f;
  uint32_t u = v.u + 0x7fffu + ((v.u >> 16) & 1u);   // RNE (finite values only)
  return (bf16u)(u >> 16);
}

// HW f32->bf16 (v_cvt class, RNE) — 1 op instead of 5-op bit twiddle.
__device__ __forceinline__ bf16u f2bf_hw(float f) {
  union { __bf16 h; bf16u u; } v; v.h = (__bf16)f; return v.u;
}

__device__ __forceinline__ float bf2f(bf16u b) {
  union { uint32_t u; float f; } v; v.u = (uint32_t)b << 16; return v.f;
}

// Raw v_exp_f32 (exp2). Plain exp2f without fast-math lowers to an OCML call
// with range/denormal fixup (~10 instrs) — this is 1 instr.
__device__ __forceinline__ float exp2_hw(float x) {
  return __builtin_amdgcn_exp2f(x);
}

// async global->LDS, 16 bytes per lane.
__device__ __forceinline__ void async_copy16(const bf16u* g, const bf16u* l) {
  __builtin_amdgcn_global_load_lds((gvoid_t*)(uintptr_t)g,
                                   (lvoid_t*)(uint32_t)(uintptr_t)l,
                                   16, 0, 0);
}

#define VM_WAIT(n) asm volatile("s_waitcnt vmcnt(" #n ")" ::: "memory")
#define LGKM0()    asm volatile("s_waitcnt lgkmcnt(0)" ::: "memory")
#define BARRIER()  asm volatile("s_barrier" ::: "memory")

// ---------------- LayerNorm (fp32 in -> bf16 out) ----------------
__global__ __launch_bounds__(256) void ln_kernel(const float* __restrict__ x,
                                                 const float* __restrict__ g,
                                                 const float* __restrict__ be,
                                                 bf16u* __restrict__ out) {
  const int row = blockIdx.x;
  const int t = threadIdx.x;
  const float4 v = ((const float4*)(x + (size_t)row * DM))[t];
  float s  = v.x + v.y + v.z + v.w;
  float ss = v.x * v.x + v.y * v.y + v.z * v.z + v.w * v.w;
#pragma unroll
  for (int m = 1; m < 64; m <<= 1) {
    s  += __shfl_xor(s, m, 64);
    ss += __shfl_xor(ss, m, 64);
  }
  __shared__ float red[2][4];
  const int wv = t >> 6, ln = t & 63;
  if (ln == 0) { red[0][wv] = s; red[1][wv] = ss; }
  __syncthreads();
  s  = red[0][0] + red[0][1] + red[0][2] + red[0][3];
  ss = red[1][0] + red[1][1] + red[1][2] + red[1][3];
  const float mu = s * (1.0f / DM);
  const float var = ss * (1.0f / DM) - mu * mu;
  const float rstd = rsqrtf(var + 1e-5f);
  const float4 gg = ((const float4*)g)[t];
  const float4 bb = ((const float4*)be)[t];
  u16x4 o;
  o[0] = f2bf((v.x - mu) * rstd * gg.x + bb.x);
  o[1] = f2bf((v.y - mu) * rstd * gg.y + bb.y);
  o[2] = f2bf((v.z - mu) * rstd * gg.z + bb.z);
  o[3] = f2bf((v.w - mu) * rstd * gg.w + bb.w);
  *(u16x4*)(out + (size_t)row * DM + t * 4) = o;
}

// ---------------- fused preprocessing: LN1 + all weight transposes ----------
// blocks 0..4095: LN rows | 4096..8191: wq/wk/wv/wo 32x32 tiles |
// 8192..12287: w1 (1024x4096) | 12288..16383: w2 (4096x1024).
__global__ __launch_bounds__(256) void prep_kernel(
    const float* __restrict__ x, const float* __restrict__ g,
    const float* __restrict__ be, bf16u* __restrict__ lnout,
    const float* __restrict__ wq, const float* __restrict__ wk,
    const float* __restrict__ wv_, const float* __restrict__ wo,
    bf16u* __restrict__ wqkv_t,
    const float* __restrict__ w1, bf16u* __restrict__ w1_t,
    const float* __restrict__ w2, bf16u* __restrict__ w2_t) {
  const int bid = blockIdx.x;
  const int t = threadIdx.x;
  if (bid < 4096) {
    const int row = bid;
    const float4 v = ((const float4*)(x + (size_t)row * DM))[t];
    float s  = v.x + v.y + v.z + v.w;
    float ss = v.x * v.x + v.y * v.y + v.z * v.z + v.w * v.w;
#pragma unroll
    for (int m = 1; m < 64; m <<= 1) {
      s  += __shfl_xor(s, m, 64);
      ss += __shfl_xor(ss, m, 64);
    }
    __shared__ float red[2][4];
    const int wv = t >> 6, ln = t & 63;
    if (ln == 0) { red[0][wv] = s; red[1][wv] = ss; }
    __syncthreads();
    s  = red[0][0] + red[0][1] + red[0][2] + red[0][3];
    ss = red[1][0] + red[1][1] + red[1][2] + red[1][3];
    const float mu = s * (1.0f / DM);
    const float var = ss * (1.0f / DM) - mu * mu;
    const float rstd = rsqrtf(var + 1e-5f);
    const float4 gg = ((const float4*)g)[t];
    const float4 bb = ((const float4*)be)[t];
    u16x4 o;
    o[0] = f2bf((v.x - mu) * rstd * gg.x + bb.x);
    o[1] = f2bf((v.y - mu) * rstd * gg.y + bb.y);
    o[2] = f2bf((v.z - mu) * rstd * gg.z + bb.z);
    o[3] = f2bf((v.w - mu) * rstd * gg.w + bb.w);
    *(u16x4*)(lnout + (size_t)row * DM + t * 4) = o;
    return;
  }
  __shared__ float tile[32][33];
  const int tx = t & 31, ty = t >> 5;
  const float* in; bf16u* o; int R, C, c0, r0;
  if (bid < 8192) {
    const int idx = bid - 4096;
    const int mat = idx >> 10, rem = idx & 1023;
    const float* srcs[4] = {wq, wk, wv_, wo};
    in = srcs[mat]; o = wqkv_t + (size_t)mat * 1024 * 1024;   // wo lands at wo_t
    R = 1024; C = 1024;
    c0 = (rem & 31) * 32; r0 = (rem >> 5) * 32;
  } else if (bid < 12288) {
    const int idx = bid - 8192;
    in = w1; o = w1_t; R = 1024; C = 4096;
    c0 = (idx & 127) * 32; r0 = (idx >> 7) * 32;
  } else {
    const int idx = bid - 12288;
    in = w2; o = w2_t; R = 4096; C = 1024;
    c0 = (idx & 31) * 32; r0 = (idx >> 5) * 32;
  }
#pragma unroll
  for (int i = 0; i < 4; ++i)
    tile[ty + i * 8][tx] = in[(size_t)(r0 + ty + i * 8) * C + c0 + tx];
  __syncthreads();
#pragma unroll
  for (int i = 0; i < 4; ++i)
    o[(size_t)(c0 + ty + i * 8) * R + r0 + tx] = f2bf(tile[tx][ty + i * 8]);
}

// ---------------- GEMM 128x128, BK=64, 8-phase pipelined, 2 blocks/CU -------
// (R12 kernel — best measured: 42.7 µs on the big shapes, passing.)
// 256 threads = 4 waves (2M x 2N), per-wave C = 64x64 => acc[4][4] (AGPRs).
// LDS 64 KiB: 2 bufs x (A 128x64 + B 128x64) bf16 => 2 blocks/CU co-resident.
// PHASE/QUARTER INVARIANT: phase (mh) reads A rows wm*64 + mh*32 + [0,32)
// = {mh*32..} U {64+mh*32..}. Quarters are ROW-PERMUTED: quarter q, lds row
// lr -> global row (lr&31) + (lr>>5)*64 + q*32, so each phase's reads hit
// exactly ONE landed quarter under the counted VM_WAIT(4) chain (4 loads
// always in flight). Reads map row r -> ((r>>5)&1)*4096 +
// ((r&31) + (r>>6)*32)*64; swizzle bit r&7 == lr&7.
// 16B slots XOR-swizzled by row&7 (conflict-free ds_read_b128).
// mode 0: bf16 | 1: +bias,relu,bf16 | 5: QKV fused (Q pre-scale n0<1024,
// V^T emit n0>=2048) | 7: fp32 accumulate: outF += acc + bias (FFN2; outF
// already holds attn@wo + x residual; each element owned by ONE block).
__global__ __launch_bounds__(256, 2) void gemm256(
    const bf16u* __restrict__ A, const bf16u* __restrict__ Bt,
    int M, int N, int K,
    const float* __restrict__ bias, bf16u* __restrict__ outB,
    bf16u* __restrict__ vt, float* __restrict__ outF, int mode) {
  __shared__ bf16u sh[2][16384];
  const int t = threadIdx.x;
  const int ln = t & 63;
  const int wv = t >> 6;
  const int col16 = ln & 15, quad = ln >> 4;
  const int wm = wv >> 1, wn = wv & 1;

  // T1: XCD-aware swizzle of the 1-D grid (nwg % 8 == 0 for our shapes)
  const int nbx = N >> 7;
  const int nwg = nbx * (M >> 7);
  const int cpx = nwg >> 3;
  const int bid = blockIdx.x;
  const int swz = (bid & 7) * cpx + (bid >> 3);
  const int m0 = (swz / nbx) << 7, n0 = (swz % nbx) << 7;
  const int nt = K >> 6;

  // staging sources: 4 stage-steps (Aq0,Bq0,Bq1,Aq1) x 2 chunks/thread.
  const bf16u* gsrc[4][2];
  int doff[4][2];
#pragma unroll
  for (int j = 0; j < 2; ++j) {
    const int c = t + (j << 8);            // 0..511
    const int lr = c >> 3, slot = (c & 7) ^ (lr & 7);
    const int rq = (lr & 31) + ((lr >> 5) << 6);   // quarter row permutation
    gsrc[0][j] = A  + (size_t)(m0 + rq) * K + slot * 8;        // Aq0 {0-31,64-95}
    gsrc[3][j] = A  + (size_t)(m0 + rq + 32) * K + slot * 8;   // Aq1 {32-63,96-127}
    gsrc[1][j] = Bt + (size_t)(n0 + rq) * K + slot * 8;        // Bq0
    gsrc[2][j] = Bt + (size_t)(n0 + rq + 32) * K + slot * 8;   // Bq1
    doff[0][j] = c * 8;                    // Aq0 -> [0, 4096)
    doff[3][j] = 4096 + c * 8;             // Aq1 -> [4096, 8192)
    doff[1][j] = 8192 + c * 8;             // Bq0 -> [8192, 12288)
    doff[2][j] = 12288 + c * 8;            // Bq1 -> [12288, 16384)
  }

  // ds_read offsets; row r lives at quarter ((r>>5)&1), lds row (r&31)+(r>>6)*32.
  int aoffs[4][2], boffs[4][2];
#pragma unroll
  for (int i = 0; i < 4; ++i)
#pragma unroll
    for (int kc = 0; kc < 2; ++kc) {
      const int ra = wm * 64 + i * 16 + col16;
      const int la = ((ra >> 5) & 1) * 4096 + (((ra & 31) + ((ra >> 6) << 5)) << 6);
      aoffs[i][kc] = la + (((kc << 2) + quad) ^ (ra & 7)) * 8;
      const int rb = wn * 64 + i * 16 + col16;
      const int lb = ((rb >> 5) & 1) * 4096 + (((rb & 31) + ((rb >> 6) << 5)) << 6);
      boffs[i][kc] = 8192 + lb + (((kc << 2) + quad) ^ (rb & 7)) * 8;
    }

  f32x4 acc[4][4] = {};
  bf16x8 Af[2][2], Bf[4][2];

  auto stage = [&](int s, int b) {
#pragma unroll
    for (int j = 0; j < 2; ++j) {
      async_copy16(gsrc[s][j], &sh[b][doff[s][j]]);
      gsrc[s][j] += 64;
    }
  };
  auto readA = [&](int b, int mh) {
#pragma unroll
    for (int i = 0; i < 2; ++i)
#pragma unroll
      for (int kc = 0; kc < 2; ++kc)
        Af[i][kc] = *(const bf16x8*)(&sh[b][aoffs[mh * 2 + i][kc]]);
  };
  auto readB = [&](int b, int nh) {
#pragma unroll
    for (int i = 0; i < 2; ++i)
#pragma unroll
      for (int kc = 0; kc < 2; ++kc)
        Bf[nh * 2 + i][kc] = *(const bf16x8*)(&sh[b][boffs[nh * 2 + i][kc]]);
  };
  auto mfmaQ = [&](int mh, int nh) {
#pragma unroll
    for (int kc = 0; kc < 2; ++kc)
#pragma unroll
      for (int mi = 0; mi < 2; ++mi)
#pragma unroll
        for (int nl = 0; nl < 2; ++nl)
          acc[mh * 2 + mi][nh * 2 + nl] = __builtin_amdgcn_mfma_f32_16x16x32_bf16(
              Af[mi][kc], Bf[nh * 2 + nl][kc], acc[mh * 2 + mi][nh * 2 + nl], 0, 0, 0);
  };

  stage(0, 0); stage(1, 0); stage(2, 0); stage(3, 0);
  VM_WAIT(4);                // Aq0+Bq0 of tile 0 landed; 2 quarters in flight
  BARRIER();

  int bsel = 0;
  for (int kt = 0; kt < nt - 1; ++kt, bsel ^= 1) {
    const int bn = bsel ^ 1;
    // phase 1: quadrant (0,0) — needs Aq0+Bq0 (landed)
    readA(bsel, 0); readB(bsel, 0);
    stage(0, bn);
    BARRIER(); LGKM0();
    __builtin_amdgcn_s_setprio(1); mfmaQ(0, 0); __builtin_amdgcn_s_setprio(0);
    VM_WAIT(4); BARRIER();   // retires Bq1(cur)
    // phase 2: quadrant (0,1) — needs Bq1
    readB(bsel, 1);
    stage(1, bn);
    BARRIER(); LGKM0();
    __builtin_amdgcn_s_setprio(1); mfmaQ(0, 1); __builtin_amdgcn_s_setprio(0);
    VM_WAIT(4); BARRIER();   // retires Aq1(cur)
    // phase 3: quadrant (1,0) — needs Aq1
    readA(bsel, 1);
    stage(2, bn);
    BARRIER(); LGKM0();
    __builtin_amdgcn_s_setprio(1); mfmaQ(1, 0); __builtin_amdgcn_s_setprio(0);
    BARRIER();
    // phase 4: quadrant (1,1) — pure MFMA (reuses Af[1]/Bf[2..3])
    stage(3, bn);
    __builtin_amdgcn_s_setprio(1); mfmaQ(1, 1); __builtin_amdgcn_s_setprio(0);
    VM_WAIT(4); BARRIER();   // retires Aq0(next)+Bq0(next)
  }
  // final tile: no staging, progressive drain 4 -> 2 -> 0
  readA(bsel, 0); readB(bsel, 0);
  BARRIER(); LGKM0();
  __builtin_amdgcn_s_setprio(1); mfmaQ(0, 0); __builtin_amdgcn_s_setprio(0);
  VM_WAIT(2); BARRIER();
  readB(bsel, 1);
  BARRIER(); LGKM0();
  __builtin_amdgcn_s_setprio(1); mfmaQ(0, 1); __builtin_amdgcn_s_setprio(0);
  VM_WAIT(0); BARRIER();
  readA(bsel, 1);
  LGKM0();
  __builtin_amdgcn_s_setprio(1); mfmaQ(1, 0); mfmaQ(1, 1); __builtin_amdgcn_s_setprio(0);

  // ---- epilogue ----
  if (mode == 7) {
    // FFN2: fp32 accumulate into outF (= attn@wo + x residual) + bias.
    float bv[4];
#pragma unroll
    for (int n = 0; n < 4; ++n) bv[n] = bias[n0 + wn * 64 + n * 16 + col16];
#pragma unroll
    for (int mi = 0; mi < 4; ++mi) {
#pragma unroll
      for (int n = 0; n < 4; ++n) {
        const int col = n0 + wn * 64 + n * 16 + col16;
#pragma unroll
        for (int r = 0; r < 4; ++r) {
          const int row = m0 + wm * 64 + mi * 16 + quad * 4 + r;
          const size_t idx = (size_t)row * N + col;
          outF[idx] = outF[idx] + acc[mi][n][r] + bv[n];
        }
      }
    }
    return;
  }
  if (mode == 5 && n0 >= 2048) {
    // fused vtrans: V section -> vt[(b*16+h)*64 + d][s], packed 8B stores.
#pragma unroll
    for (int mi = 0; mi < 4; ++mi) {
#pragma unroll
      for (int n = 0; n < 4; ++n) {
        const int col = n0 + wn * 64 + n * 16 + col16;
        const int hh = (col - 2048) >> 6, d = (col - 2048) & 63;
        const int row_base = m0 + wm * 64 + mi * 16 + quad * 4;
        const int bb = row_base >> 11, s = row_base & 2047;
        u16x4 o;
#pragma unroll
        for (int r = 0; r < 4; ++r) o[r] = f2bf(acc[mi][n][r]);
        *(u16x4*)(vt + (size_t)((bb * 16 + hh) * 64 + d) * SEQ + s) = o;
      }
    }
    return;
  }
  // Q pre-scale: fold softmax 1/sqrt(d)*log2(e) into the Q section of QKV.
  const float qscale = (mode == 5 && n0 < 1024) ? SCL : 1.0f;
  float bv[4];
  if (mode == 1) {
#pragma unroll
    for (int n = 0; n < 4; ++n) bv[n] = bias[n0 + wn * 64 + n * 16 + col16];
  }
#pragma unroll
  for (int mi = 0; mi < 4; ++mi) {
#pragma unroll
    for (int n = 0; n < 4; ++n) {
      const int col = n0 + wn * 64 + n * 16 + col16;
#pragma unroll
      for (int r = 0; r < 4; ++r) {
        const int row = m0 + wm * 64 + mi * 16 + quad * 4 + r;
        float v = acc[mi][n][r];
        if (mode == 1) v = fmaxf(v + bv[n], 0.0f);
        outB[(size_t)row * N + col] = f2bf(v * qscale);
      }
    }
  }
}

// ---------------- GEMM 64x128, BK=64, swizzled LDS, pipelined (wo GEMM) -----
// mode 2: +resid fp32 | 3: +bias+resid fp32
__global__ __launch_bounds__(256, 3) void gemm_bt64(
    const bf16u* __restrict__ A, const bf16u* __restrict__ Bt,
    int M, int N, int K,
    const float* __restrict__ bias, const float* __restrict__ resid,
    bf16u* __restrict__ outB, float* __restrict__ outF, int mode) {
  __shared__ bf16u As0[64 * 64], As1[64 * 64];
  __shared__ bf16u Bs0[128 * 64], Bs1[128 * 64];
  const int t = threadIdx.x;
  const int ln = t & 63;
  const int wv = t >> 6;
  const int col16 = ln & 15, quad = ln >> 4;

  const int nbx = gridDim.x;
  const int nwg = nbx * gridDim.y;          // 512 for our launches (%8==0)
  const int cpx = nwg >> 3;
  const int flat = blockIdx.y * nbx + blockIdx.x;
  const int swz = (flat & 7) * cpx + (flat >> 3);
  const int m0 = (swz / nbx) * 64, n0 = (swz % nbx) * 128;

  const bf16u* gA[2];
  const bf16u* gB[4];
#pragma unroll
  for (int j = 0; j < 2; ++j) {
    const int c = t + 256 * j, row = c >> 3, slot = (c & 7) ^ (row & 7);
    gA[j] = A + (size_t)(m0 + row) * K + slot * 8;
  }
#pragma unroll
  for (int j = 0; j < 4; ++j) {
    const int c = t + 256 * j, row = c >> 3, slot = (c & 7) ^ (row & 7);
    gB[j] = Bt + (size_t)(n0 + row) * K + slot * 8;
  }

  f32x4 acc[4][2] = {};

  auto stage = [&](bf16u* dA, bf16u* dB) {
#pragma unroll
    for (int j = 0; j < 2; ++j) {
      async_copy16(gA[j], dA + (size_t)(t + 256 * j) * 8);
      gA[j] += 64;
    }
#pragma unroll
    for (int j = 0; j < 4; ++j) {
      async_copy16(gB[j], dB + (size_t)(t + 256 * j) * 8);
      gB[j] += 64;
    }
  };
  auto compute = [&](const bf16u* sA, const bf16u* sB) {
    bf16x8 af[4][2], bfv[2][2];
#pragma unroll
    for (int mi = 0; mi < 4; ++mi) {
      const int row = mi * 16 + col16;
#pragma unroll
      for (int kc = 0; kc < 2; ++kc)
        af[mi][kc] = *(const bf16x8*)(sA + row * 64 + (((kc << 2) + quad) ^ (row & 7)) * 8);
    }
#pragma unroll
    for (int ni = 0; ni < 2; ++ni) {
      const int row = wv * 32 + ni * 16 + col16;
#pragma unroll
      for (int kc = 0; kc < 2; ++kc)
        bfv[ni][kc] = *(const bf16x8*)(sB + row * 64 + (((kc << 2) + quad) ^ (row & 7)) * 8);
    }
#pragma unroll
    for (int kc = 0; kc < 2; ++kc)
#pragma unroll
      for (int mi = 0; mi < 4; ++mi)
#pragma unroll
        for (int ni = 0; ni < 2; ++ni)
          acc[mi][ni] = __builtin_amdgcn_mfma_f32_16x16x32_bf16(af[mi][kc], bfv[ni][kc],
                                                                acc[mi][ni], 0, 0, 0);
  };

  const int niter = K >> 6;     // 16 (wo) — even
  stage(As0, Bs0);
  for (int k = 0; k < niter; k += 2) {
    stage(As1, Bs1);
    VM_WAIT(6);
    BARRIER();
    compute(As0, Bs0);
    BARRIER();
    if (k + 2 < niter) {
      stage(As0, Bs0);
      VM_WAIT(6);
    } else {
      VM_WAIT(0);
    }
    BARRIER();
    compute(As1, Bs1);
    BARRIER();
  }

#pragma unroll
  for (int mi = 0; mi < 4; ++mi) {
#pragma unroll
    for (int ni = 0; ni < 2; ++ni) {
      const int col = n0 + wv * 32 + ni * 16 + col16;
#pragma unroll
      for (int r = 0; r < 4; ++r) {
        const int row = m0 + mi * 16 + quad * 4 + r;
        float v = acc[mi][ni][r];
        if (mode == 1 || mode == 3) v += bias[col];
        if (mode == 1) v = fmaxf(v, 0.0f);
        if (mode >= 2) {
          outF[(size_t)row * N + col] = v + resid[(size_t)row * N + col];
        } else {
          outB[(size_t)row * N + col] = f2bf(v);
        }
      }
    }
  }
}

// ---------------- causal flash attention v6 + raw v_exp_f32 + setprio -------
// One 64-q-row strip per block, grid (bh=32, strips=32) heavy-first.
// Q pre-scaled by SCL at QKV epilogue. Softmax exp2 via v_exp_f32.
// Rotated software pipeline with RAW barriers + counted vmcnt.
// PV uses swapped MFMA operands -> O^T in C layout -> packed u16x4 stores.
#define PST 132   // pbuf row stride (elements): 128 keys + 4 pad
__global__ __launch_bounds__(256, 3) void attn_kernel(const bf16u* __restrict__ qkv,
                                                      const bf16u* __restrict__ vt,
                                                      bf16u* __restrict__ out) {
  __shared__ bf16u Ks[128 * 64];
  __shared__ bf16u Vts[2 * 64 * 64];
  __shared__ bf16u pbuf[4][16 * PST];
  __shared__ float lred[4][16];
  const int t = threadIdx.x;
  const int wv = t >> 6, ln = t & 63;
  const int col = ln & 15, quad = ln >> 4;
  const int bh = blockIdx.x, b = bh >> 4, h = bh & 15;
  const int strip = 31 - blockIdx.y;       // heavy blocks dispatch first
  const int q0 = strip * 64;
  const int qw = q0 + wv * 16;
  const int qmax = qw + 15;
  const int ntiles = (q0 >> 7) + 1;

  int krow[4], kslot[4], vrow[4], vsub[4], vslot[4];
  const bf16u *kl[4], *vl[4];
#pragma unroll
  for (int j = 0; j < 4; ++j) {
    const int c = t + 256 * j;
    krow[j] = c >> 3; kslot[j] = (c & 7) ^ (krow[j] & 7);
    const int rem = c & 511;
    vsub[j] = c >> 9; vrow[j] = rem >> 3; vslot[j] = (rem & 7) ^ (vrow[j] & 7);
    kl[j] = Ks + (size_t)c * 8;
    vl[j] = Vts + (size_t)c * 8;
  }

  auto stageK = [&](int kb) {
    const int kbase = kb * 128;
#pragma unroll
    for (int j = 0; j < 4; ++j)
      async_copy16(qkv + (size_t)(b * SEQ + kbase + krow[j]) * 3072 + 1024 + h * 64 + kslot[j] * 8, kl[j]);
  };
  auto stageV = [&](int kb) {
    const int kbase = kb * 128;
#pragma unroll
    for (int j = 0; j < 4; ++j)
      async_copy16(vt + (size_t)(bh * 64 + vrow[j]) * SEQ + kbase + vsub[j] * 64 + vslot[j] * 8, vl[j]);
  };

  bf16x8 qf0, qf1;
  {
    const size_t qoff = (size_t)(b * SEQ + qw + col) * 3072 + h * 64 + quad * 8;
    qf0 = *(const bf16x8*)(qkv + qoff);
    qf1 = *(const bf16x8*)(qkv + qoff + 32);
  }
  f32x4 po[4] = {};          // O^T accum: po[n] rows hd=n*16+quad*4+r, col q
  float ll[4] = {};          // per-lane softmax denominator partials

  stageK(0);
  stageV(0);
  VM_WAIT(4);                // K0 landed (+ Q regs); V0 stays in flight
  BARRIER();

  for (int kb = 0; kb < ntiles; ++kb) {
    const int kbase = kb * 128;
    if (kb < ntiles - 1) {
      // ---------- fully-unmasked 128-key tile ----------
      f32x4 sc[8];
      __builtin_amdgcn_s_setprio(1);
#pragma unroll
      for (int n = 0; n < 8; ++n) {
        const int kr = n * 16 + col;
        const bf16x8 k0 = *(const bf16x8*)(Ks + kr * 64 + (quad ^ (kr & 7)) * 8);
        const bf16x8 k1 = *(const bf16x8*)(Ks + kr * 64 + ((4 + quad) ^ (kr & 7)) * 8);
        f32x4 z = {};
        z = __builtin_amdgcn_mfma_f32_16x16x32_bf16(qf0, k0, z, 0, 0, 0);
        sc[n] = __builtin_amdgcn_mfma_f32_16x16x32_bf16(qf1, k1, z, 0, 0, 0);
      }
      __builtin_amdgcn_s_setprio(0);
#pragma unroll
      for (int r = 0; r < 4; ++r) {
#pragma unroll
        for (int n = 0; n < 8; ++n) {
          const float e = exp2_hw(sc[n][r]);
          ll[r] += e;
          pbuf[wv][(quad * 4 + r) * PST + n * 16 + col] = f2bf_hw(e);
        }
      }
    } else {
      // ---------- diagonal tile: mask + wave-uniform n-tile skip ----------
      f32x4 sc[8];
      bool act[8];
      __builtin_amdgcn_s_setprio(1);
#pragma unroll
      for (int n = 0; n < 8; ++n) {
        act[n] = (kbase + n * 16) <= qmax;
        if (act[n]) {
          const int kr = n * 16 + col;
          const bf16x8 k0 = *(const bf16x8*)(Ks + kr * 64 + (quad ^ (kr & 7)) * 8);
          const bf16x8 k1 = *(const bf16x8*)(Ks + kr * 64 + ((4 + quad) ^ (kr & 7)) * 8);
          f32x4 z = {};
          z = __builtin_amdgcn_mfma_f32_16x16x32_bf16(qf0, k0, z, 0, 0, 0);
          sc[n] = __builtin_amdgcn_mfma_f32_16x16x32_bf16(qf1, k1, z, 0, 0, 0);
        }
      }
      __builtin_amdgcn_s_setprio(0);
#pragma unroll
      for (int r = 0; r < 4; ++r) {
        const int q = qw + quad * 4 + r;
#pragma unroll
        for (int n = 0; n < 8; ++n) {
          float e = 0.0f;
          if (act[n]) {
            float v = sc[n][r];
            v = (kbase + n * 16 + col <= q) ? v : -1e30f;   // v_exp_f32 -> 0
            e = exp2_hw(v);
          }
          ll[r] += e;
          pbuf[wv][(quad * 4 + r) * PST + n * 16 + col] = f2bf_hw(e);
        }
      }
    }
    LGKM0();           // wave-local P writes done (drains Ks reads too)
    bf16x8 pa[4];
#pragma unroll
    for (int kc = 0; kc < 4; ++kc)
      pa[kc] = *(const bf16x8*)(&pbuf[wv][col * PST + kc * 32 + quad * 8]);
    VM_WAIT(0);        // V_kb landed
    BARRIER();         // all waves: Ks reads drained, Vts populated
    if (kb + 1 < ntiles) stageK(kb + 1);   // K latency hides under PV
    if (kb < ntiles - 1) {
      __builtin_amdgcn_s_setprio(1);
#pragma unroll
      for (int n = 0; n < 4; ++n) {
        const int vr = n * 16 + col;
#pragma unroll
        for (int kc = 0; kc < 4; ++kc) {
          const bf16x8 vfr = *(const bf16x8*)(Vts + (kc >> 1) * 4096 + vr * 64 +
                                              (((kc & 1) * 4 + quad) ^ (vr & 7)) * 8);
          // swapped operands: C = V^T * P^T = O^T (col=q, row=hd)
          po[n] = __builtin_amdgcn_mfma_f32_16x16x32_bf16(vfr, pa[kc], po[n], 0, 0, 0);
        }
      }
      __builtin_amdgcn_s_setprio(0);
    } else {
      __builtin_amdgcn_s_setprio(1);
#pragma unroll
      for (int n = 0; n < 4; ++n) {
        const int vr = n * 16 + col;
#pragma unroll
        for (int kc = 0; kc < 4; ++kc)
          if (kbase + kc * 32 <= qmax) {
            const bf16x8 vfr = *(const bf16x8*)(Vts + (kc >> 1) * 4096 + vr * 64 +
                                                (((kc & 1) * 4 + quad) ^ (vr & 7)) * 8);
            po[n] = __builtin_amdgcn_mfma_f32_16x16x32_bf16(vfr, pa[kc], po[n], 0, 0, 0);
          }
      }
      __builtin_amdgcn_s_setprio(0);
    }
    if (kb + 1 < ntiles) {
      LGKM0();         // own Vts reads drained
      BARRIER();       // all waves done reading Vts
      stageV(kb + 1);  // V latency hides under next QK^T+softmax
      VM_WAIT(4);      // K_{kb+1} landed (in-order retire); V in flight
      BARRIER();
    }
  }

  // reduce l across the 16 q-columns, broadcast via LDS, normalize, store O^T
#pragma unroll
  for (int m = 1; m < 16; m <<= 1)
#pragma unroll
    for (int r = 0; r < 4; ++r) ll[r] += __shfl_xor(ll[r], m, 64);
  if (col == 0) {
#pragma unroll
    for (int r = 0; r < 4; ++r) lred[wv][quad * 4 + r] = ll[r];
  }
  LGKM0();
  const float inv = 1.0f / lred[wv][col];
#pragma unroll
  for (int n = 0; n < 4; ++n) {
    u16x4 o;
#pragma unroll
    for (int r = 0; r < 4; ++r) o[r] = f2bf(po[n][r] * inv);
    *(u16x4*)(out + (size_t)(b * SEQ + qw + col) * DM + h * 64 + n * 16 + quad * 4) = o;
  }
}

// ---------------- launch ----------------
extern "C" void kernel_launch(void* const* d_in, const int* in_sizes, int n_in,
                              void* d_out, int out_size, void* d_ws, size_t ws_size,
                              hipStream_t stream) {
  const float* x   = (const float*)d_in[0];
  const float* wq  = (const float*)d_in[1];
  const float* wk  = (const float*)d_in[2];
  const float* wvv = (const float*)d_in[3];
  const float* wo  = (const float*)d_in[4];
  const float* w1  = (const float*)d_in[5];
  const float* b1  = (const float*)d_in[6];
  const float* w2  = (const float*)d_in[7];
  const float* b2  = (const float*)d_in[8];
  const float* g1  = (const float*)d_in[9];
  const float* be1 = (const float*)d_in[10];
  const float* g2  = (const float*)d_in[11];
  const float* be2 = (const float*)d_in[12];
  float* out = (float*)d_out;

  char* ws = (char*)d_ws;
  bf16u* wqkv_t = (bf16u*)(ws);              //  0 ..  6 MB  (3072 x 1024)
  bf16u* wo_t   = (bf16u*)(ws +  6291456);   //  6 ..  8 MB  (1024 x 1024)
  bf16u* w1_t   = (bf16u*)(ws +  8388608);   //  8 .. 16 MB  (4096 x 1024)
  bf16u* w2_t   = (bf16u*)(ws + 16777216);   // 16 .. 24 MB  (1024 x 4096)
  bf16u* lnbuf  = (bf16u*)(ws + 25165824);   // 24 .. 32 MB  (4096 x 1024) also attn out
  bf16u* qkv    = (bf16u*)(ws + 33554432);   // 32 .. 56 MB  (4096 x 3072)
  bf16u* vtb    = (bf16u*)(ws + 58720256);   // 56 .. 64 MB  (32 x 64 x 2048)
  bf16u* h1     = (bf16u*)(ws + 33554432);   // 32 .. 64 MB  (reuse: 4096 x 4096)
  bf16u* attn   = lnbuf;                     // ln1 dead after QKV GEMM

  // fused preprocessing: LN1 + all weight transposes in ONE launch
  prep_kernel<<<16384, 256, 0, stream>>>(x, g1, be1, lnbuf,
                                         wq, wk, wvv, wo, wqkv_t,
                                         w1, w1_t, w2, w2_t);
  // QKV with fused V-transpose + Q pre-scale (mode 5). 128x128 tiles.
  gemm256<<<768, 256, 0, stream>>>(lnbuf, wqkv_t, 4096, 3072, 1024,
                                   nullptr, qkv, vtb, nullptr, 5);
  attn_kernel<<<dim3(32, 32), 256, 0, stream>>>(qkv, vtb, attn);
  gemm_bt64<<<dim3(8, 64), 256, 0, stream>>>(attn, wo_t, 4096, 1024, 1024,
                                             nullptr, x, nullptr, out, 2);
  ln_kernel<<<4096, 256, 0, stream>>>(out, g2, be2, lnbuf);
  gemm256<<<1024, 256, 0, stream>>>(lnbuf, w1_t, 4096, 4096, 1024,
                                    b1, h1, nullptr, nullptr, 1);
  // FFN2: UNSPLIT (256 blocks x K=4096 = 64 iters — deepest K-amortization;
  // R10/R12 evidence: dispatch time ~independent of per-block K, so split-K
  // bought nothing while costing a 10 µs reduce pass + 48 MB traffic).
  // mode 7 accumulates directly into out (attn@wo + x residual) + bias.
  gemm256<<<256, 256, 0, stream>>>(h1, w2_t, 4096, 1024, 4096,
                                   b2, nullptr, nullptr, out, 7);
}

// Round 15
// 303.767 us; speedup vs baseline: 1.1066x; 1.0674x over previous
//
#include <hip/hip_runtime.h>
#include <stdint.h>

// ---------------- types / helpers ----------------
typedef unsigned short bf16u;                                    // raw bf16 bits
typedef __attribute__((ext_vector_type(8))) __bf16 bf16x8;       // MFMA A/B frag
typedef __attribute__((ext_vector_type(4))) float f32x4;         // MFMA C/D frag
typedef __attribute__((ext_vector_type(4))) unsigned short u16x4;
typedef __attribute__((ext_vector_type(8))) unsigned short u16x8;

typedef __attribute__((address_space(1))) void gvoid_t;
typedef __attribute__((address_space(3))) void lvoid_t;

#define SEQ 2048
#define DM 1024
#define MN22 4194304   // 4096*1024
#define SCL 0.18033688f   // (1/8) * log2(e) — folded into Q at QKV epilogue

__device__ __forceinline__ bf16u f2bf(float f) {
  union { float f; uint32_t u; } v; v.f = f;
  uint32_t u = v.u + 0x7fffu + ((v.u >> 16) & 1u);   // RNE (finite values only)
  return (bf16u)(u >> 16);
}

// HW f32->bf16 (v_cvt class, RNE) — 1 op instead of 5-op bit twiddle.
__device__ __forceinline__ bf16u f2bf_hw(float f) {
  union { __bf16 h; bf16u u; } v; v.h = (__bf16)f; return v.u;
}

__device__ __forceinline__ float bf2f(bf16u b) {
  union { uint32_t u; float f; } v; v.u = (uint32_t)b << 16; return v.f;
}

// Raw v_exp_f32 (exp2). Plain exp2f without fast-math lowers to an OCML call
// with range/denormal fixup (~10 instrs) — this is 1 instr.
__device__ __forceinline__ float exp2_hw(float x) {
  return __builtin_amdgcn_exp2f(x);
}

// async global->LDS, 16 bytes per lane.
__device__ __forceinline__ void async_copy16(const bf16u* g, const bf16u* l) {
  __builtin_amdgcn_global_load_lds((gvoid_t*)(uintptr_t)g,
                                   (lvoid_t*)(uint32_t)(uintptr_t)l,
                                   16, 0, 0);
}

#define VM_WAIT(n) asm volatile("s_waitcnt vmcnt(" #n ")" ::: "memory")
#define LGKM0()    asm volatile("s_waitcnt lgkmcnt(0)" ::: "memory")
#define BARRIER()  asm volatile("s_barrier" ::: "memory")

// ---------------- LayerNorm (fp32 in -> bf16 out) ----------------
__global__ __launch_bounds__(256) void ln_kernel(const float* __restrict__ x,
                                                 const float* __restrict__ g,
                                                 const float* __restrict__ be,
                                                 bf16u* __restrict__ out) {
  const int row = blockIdx.x;
  const int t = threadIdx.x;
  const float4 v = ((const float4*)(x + (size_t)row * DM))[t];
  float s  = v.x + v.y + v.z + v.w;
  float ss = v.x * v.x + v.y * v.y + v.z * v.z + v.w * v.w;
#pragma unroll
  for (int m = 1; m < 64; m <<= 1) {
    s  += __shfl_xor(s, m, 64);
    ss += __shfl_xor(ss, m, 64);
  }
  __shared__ float red[2][4];
  const int wv = t >> 6, ln = t & 63;
  if (ln == 0) { red[0][wv] = s; red[1][wv] = ss; }
  __syncthreads();
  s  = red[0][0] + red[0][1] + red[0][2] + red[0][3];
  ss = red[1][0] + red[1][1] + red[1][2] + red[1][3];
  const float mu = s * (1.0f / DM);
  const float var = ss * (1.0f / DM) - mu * mu;
  const float rstd = rsqrtf(var + 1e-5f);
  const float4 gg = ((const float4*)g)[t];
  const float4 bb = ((const float4*)be)[t];
  u16x4 o;
  o[0] = f2bf((v.x - mu) * rstd * gg.x + bb.x);
  o[1] = f2bf((v.y - mu) * rstd * gg.y + bb.y);
  o[2] = f2bf((v.z - mu) * rstd * gg.z + bb.z);
  o[3] = f2bf((v.w - mu) * rstd * gg.w + bb.w);
  *(u16x4*)(out + (size_t)row * DM + t * 4) = o;
}

// ---------------- fused preprocessing: LN1 + all weight transposes ----------
// blocks 0..4095: LN rows | 4096..8191: wq/wk/wv/wo 32x32 tiles |
// 8192..12287: w1 (1024x4096) | 12288..16383: w2 (4096x1024).
__global__ __launch_bounds__(256) void prep_kernel(
    const float* __restrict__ x, const float* __restrict__ g,
    const float* __restrict__ be, bf16u* __restrict__ lnout,
    const float* __restrict__ wq, const float* __restrict__ wk,
    const float* __restrict__ wv_, const float* __restrict__ wo,
    bf16u* __restrict__ wqkv_t,
    const float* __restrict__ w1, bf16u* __restrict__ w1_t,
    const float* __restrict__ w2, bf16u* __restrict__ w2_t) {
  const int bid = blockIdx.x;
  const int t = threadIdx.x;
  if (bid < 4096) {
    const int row = bid;
    const float4 v = ((const float4*)(x + (size_t)row * DM))[t];
    float s  = v.x + v.y + v.z + v.w;
    float ss = v.x * v.x + v.y * v.y + v.z * v.z + v.w * v.w;
#pragma unroll
    for (int m = 1; m < 64; m <<= 1) {
      s  += __shfl_xor(s, m, 64);
      ss += __shfl_xor(ss, m, 64);
    }
    __shared__ float red[2][4];
    const int wv = t >> 6, ln = t & 63;
    if (ln == 0) { red[0][wv] = s; red[1][wv] = ss; }
    __syncthreads();
    s  = red[0][0] + red[0][1] + red[0][2] + red[0][3];
    ss = red[1][0] + red[1][1] + red[1][2] + red[1][3];
    const float mu = s * (1.0f / DM);
    const float var = ss * (1.0f / DM) - mu * mu;
    const float rstd = rsqrtf(var + 1e-5f);
    const float4 gg = ((const float4*)g)[t];
    const float4 bb = ((const float4*)be)[t];
    u16x4 o;
    o[0] = f2bf((v.x - mu) * rstd * gg.x + bb.x);
    o[1] = f2bf((v.y - mu) * rstd * gg.y + bb.y);
    o[2] = f2bf((v.z - mu) * rstd * gg.z + bb.z);
    o[3] = f2bf((v.w - mu) * rstd * gg.w + bb.w);
    *(u16x4*)(lnout + (size_t)row * DM + t * 4) = o;
    return;
  }
  __shared__ float tile[32][33];
  const int tx = t & 31, ty = t >> 5;
  const float* in; bf16u* o; int R, C, c0, r0;
  if (bid < 8192) {
    const int idx = bid - 4096;
    const int mat = idx >> 10, rem = idx & 1023;
    const float* srcs[4] = {wq, wk, wv_, wo};
    in = srcs[mat]; o = wqkv_t + (size_t)mat * 1024 * 1024;   // wo lands at wo_t
    R = 1024; C = 1024;
    c0 = (rem & 31) * 32; r0 = (rem >> 5) * 32;
  } else if (bid < 12288) {
    const int idx = bid - 8192;
    in = w1; o = w1_t; R = 1024; C = 4096;
    c0 = (idx & 127) * 32; r0 = (idx >> 7) * 32;
  } else {
    const int idx = bid - 12288;
    in = w2; o = w2_t; R = 4096; C = 1024;
    c0 = (idx & 31) * 32; r0 = (idx >> 5) * 32;
  }
#pragma unroll
  for (int i = 0; i < 4; ++i)
    tile[ty + i * 8][tx] = in[(size_t)(r0 + ty + i * 8) * C + c0 + tx];
  __syncthreads();
#pragma unroll
  for (int i = 0; i < 4; ++i)
    o[(size_t)(c0 + ty + i * 8) * R + r0 + tx] = f2bf(tile[tx][ty + i * 8]);
}

// ---------------- split-K combine: out += p0 + p1 + bias ----------------
__global__ __launch_bounds__(256) void reduce2(const bf16u* __restrict__ p01,
                                               const float* __restrict__ bias,
                                               float* __restrict__ out) {
  const size_t i8 = ((size_t)blockIdx.x * 256 + threadIdx.x) * 8;
  const int col0 = (int)(i8 & 1023);
  const u16x8 a = *(const u16x8*)(p01 + i8);
  const u16x8 b = *(const u16x8*)(p01 + MN22 + i8);
  const float4 o0 = *(const float4*)(out + i8);
  const float4 o1 = *(const float4*)(out + i8 + 4);
  const float4 b0 = *(const float4*)(bias + col0);
  const float4 b1 = *(const float4*)(bias + col0 + 4);
  float r[8];
#pragma unroll
  for (int j = 0; j < 8; ++j) r[j] = bf2f(a[j]) + bf2f(b[j]);
  float4 w0, w1;
  w0.x = o0.x + r[0] + b0.x; w0.y = o0.y + r[1] + b0.y;
  w0.z = o0.z + r[2] + b0.z; w0.w = o0.w + r[3] + b0.w;
  w1.x = o1.x + r[4] + b1.x; w1.y = o1.y + r[5] + b1.y;
  w1.z = o1.z + r[6] + b1.z; w1.w = o1.w + r[7] + b1.w;
  *(float4*)(out + i8) = w0;
  *(float4*)(out + i8 + 4) = w1;
}

// ---------------- GEMM 128x128, BK=64, 8-phase pipelined, 2 blocks/CU -------
// (R12 kernel — best measured: 42.7 µs on the big shapes, passing.)
// 256 threads = 4 waves (2M x 2N), per-wave C = 64x64 => acc[4][4] (AGPRs).
// LDS 64 KiB: 2 bufs x (A 128x64 + B 128x64) bf16 => 2 blocks/CU co-resident.
// PHASE/QUARTER INVARIANT: phase (mh) reads A rows wm*64 + mh*32 + [0,32)
// = {mh*32..} U {64+mh*32..}. Quarters are ROW-PERMUTED: quarter q, lds row
// lr -> global row (lr&31) + (lr>>5)*64 + q*32, so each phase's reads hit
// exactly ONE landed quarter under the counted VM_WAIT(4) chain (4 loads
// always in flight). Reads map row r -> ((r>>5)&1)*4096 +
// ((r&31) + (r>>6)*32)*64; swizzle bit r&7 == lr&7.
// 16B slots XOR-swizzled by row&7 (conflict-free ds_read_b128).
// mode 0: bf16 | 1: +bias,relu,bf16 | 5: QKV fused (Q pre-scale n0<1024,
// V^T emit n0>=2048) | 6: split-K=2 bf16 partials -> outB + split*M*N
// (combined by reduce2; 512 blocks = exactly 2/CU, K=2048/block).
__global__ __launch_bounds__(256, 2) void gemm256(
    const bf16u* __restrict__ A, const bf16u* __restrict__ Bt,
    int M, int N, int K,
    const float* __restrict__ bias, bf16u* __restrict__ outB,
    bf16u* __restrict__ vt, int mode) {
  __shared__ bf16u sh[2][16384];
  const int t = threadIdx.x;
  const int ln = t & 63;
  const int wv = t >> 6;
  const int col16 = ln & 15, quad = ln >> 4;
  const int wm = wv >> 1, wn = wv & 1;

  // T1: XCD-aware swizzle of the 1-D grid (nwg % 8 == 0 for our shapes)
  const int nsplit = (mode == 6) ? 2 : 1;
  const int nbx = N >> 7;
  const int nwg = nbx * (M >> 7) * nsplit;
  const int cpx = nwg >> 3;
  const int bid = blockIdx.x;
  const int swz = (bid & 7) * cpx + (bid >> 3);
  const int tile = swz / nsplit, split = swz - tile * nsplit;
  const int m0 = (tile / nbx) << 7, n0 = (tile % nbx) << 7;
  // K-range of this split (in BK=64 steps)
  const int tsteps = K >> 6;
  const int kbeg = (split * tsteps) / nsplit;
  const int nt = ((split + 1) * tsteps) / nsplit - kbeg;
  const size_t koff = (size_t)kbeg << 6;

  // staging sources: 4 stage-steps (Aq0,Bq0,Bq1,Aq1) x 2 chunks/thread.
  const bf16u* gsrc[4][2];
  int doff[4][2];
#pragma unroll
  for (int j = 0; j < 2; ++j) {
    const int c = t + (j << 8);            // 0..511
    const int lr = c >> 3, slot = (c & 7) ^ (lr & 7);
    const int rq = (lr & 31) + ((lr >> 5) << 6);   // quarter row permutation
    gsrc[0][j] = A  + (size_t)(m0 + rq) * K + koff + slot * 8;        // Aq0
    gsrc[3][j] = A  + (size_t)(m0 + rq + 32) * K + koff + slot * 8;   // Aq1
    gsrc[1][j] = Bt + (size_t)(n0 + rq) * K + koff + slot * 8;        // Bq0
    gsrc[2][j] = Bt + (size_t)(n0 + rq + 32) * K + koff + slot * 8;   // Bq1
    doff[0][j] = c * 8;                    // Aq0 -> [0, 4096)
    doff[3][j] = 4096 + c * 8;             // Aq1 -> [4096, 8192)
    doff[1][j] = 8192 + c * 8;             // Bq0 -> [8192, 12288)
    doff[2][j] = 12288 + c * 8;            // Bq1 -> [12288, 16384)
  }

  // ds_read offsets; row r lives at quarter ((r>>5)&1), lds row (r&31)+(r>>6)*32.
  int aoffs[4][2], boffs[4][2];
#pragma unroll
  for (int i = 0; i < 4; ++i)
#pragma unroll
    for (int kc = 0; kc < 2; ++kc) {
      const int ra = wm * 64 + i * 16 + col16;
      const int la = ((ra >> 5) & 1) * 4096 + (((ra & 31) + ((ra >> 6) << 5)) << 6);
      aoffs[i][kc] = la + (((kc << 2) + quad) ^ (ra & 7)) * 8;
      const int rb = wn * 64 + i * 16 + col16;
      const int lb = ((rb >> 5) & 1) * 4096 + (((rb & 31) + ((rb >> 6) << 5)) << 6);
      boffs[i][kc] = 8192 + lb + (((kc << 2) + quad) ^ (rb & 7)) * 8;
    }

  f32x4 acc[4][4] = {};
  bf16x8 Af[2][2], Bf[4][2];

  auto stage = [&](int s, int b) {
#pragma unroll
    for (int j = 0; j < 2; ++j) {
      async_copy16(gsrc[s][j], &sh[b][doff[s][j]]);
      gsrc[s][j] += 64;
    }
  };
  auto readA = [&](int b, int mh) {
#pragma unroll
    for (int i = 0; i < 2; ++i)
#pragma unroll
      for (int kc = 0; kc < 2; ++kc)
        Af[i][kc] = *(const bf16x8*)(&sh[b][aoffs[mh * 2 + i][kc]]);
  };
  auto readB = [&](int b, int nh) {
#pragma unroll
    for (int i = 0; i < 2; ++i)
#pragma unroll
      for (int kc = 0; kc < 2; ++kc)
        Bf[nh * 2 + i][kc] = *(const bf16x8*)(&sh[b][boffs[nh * 2 + i][kc]]);
  };
  auto mfmaQ = [&](int mh, int nh) {
#pragma unroll
    for (int kc = 0; kc < 2; ++kc)
#pragma unroll
      for (int mi = 0; mi < 2; ++mi)
#pragma unroll
        for (int nl = 0; nl < 2; ++nl)
          acc[mh * 2 + mi][nh * 2 + nl] = __builtin_amdgcn_mfma_f32_16x16x32_bf16(
              Af[mi][kc], Bf[nh * 2 + nl][kc], acc[mh * 2 + mi][nh * 2 + nl], 0, 0, 0);
  };

  stage(0, 0); stage(1, 0); stage(2, 0); stage(3, 0);
  VM_WAIT(4);                // Aq0+Bq0 of tile 0 landed; 2 quarters in flight
  BARRIER();

  int bsel = 0;
  for (int kt = 0; kt < nt - 1; ++kt, bsel ^= 1) {
    const int bn = bsel ^ 1;
    // phase 1: quadrant (0,0) — needs Aq0+Bq0 (landed)
    readA(bsel, 0); readB(bsel, 0);
    stage(0, bn);
    BARRIER(); LGKM0();
    __builtin_amdgcn_s_setprio(1); mfmaQ(0, 0); __builtin_amdgcn_s_setprio(0);
    VM_WAIT(4); BARRIER();   // retires Bq1(cur)
    // phase 2: quadrant (0,1) — needs Bq1
    readB(bsel, 1);
    stage(1, bn);
    BARRIER(); LGKM0();
    __builtin_amdgcn_s_setprio(1); mfmaQ(0, 1); __builtin_amdgcn_s_setprio(0);
    VM_WAIT(4); BARRIER();   // retires Aq1(cur)
    // phase 3: quadrant (1,0) — needs Aq1
    readA(bsel, 1);
    stage(2, bn);
    BARRIER(); LGKM0();
    __builtin_amdgcn_s_setprio(1); mfmaQ(1, 0); __builtin_amdgcn_s_setprio(0);
    BARRIER();
    // phase 4: quadrant (1,1) — pure MFMA (reuses Af[1]/Bf[2..3])
    stage(3, bn);
    __builtin_amdgcn_s_setprio(1); mfmaQ(1, 1); __builtin_amdgcn_s_setprio(0);
    VM_WAIT(4); BARRIER();   // retires Aq0(next)+Bq0(next)
  }
  // final tile: no staging, progressive drain 4 -> 2 -> 0
  readA(bsel, 0); readB(bsel, 0);
  BARRIER(); LGKM0();
  __builtin_amdgcn_s_setprio(1); mfmaQ(0, 0); __builtin_amdgcn_s_setprio(0);
  VM_WAIT(2); BARRIER();
  readB(bsel, 1);
  BARRIER(); LGKM0();
  __builtin_amdgcn_s_setprio(1); mfmaQ(0, 1); __builtin_amdgcn_s_setprio(0);
  VM_WAIT(0); BARRIER();
  readA(bsel, 1);
  LGKM0();
  __builtin_amdgcn_s_setprio(1); mfmaQ(1, 0); mfmaQ(1, 1); __builtin_amdgcn_s_setprio(0);

  // ---- epilogue ----
  if (mode == 6) {
    bf16u* pb = outB + (size_t)split * MN22;
#pragma unroll
    for (int mi = 0; mi < 4; ++mi) {
#pragma unroll
      for (int n = 0; n < 4; ++n) {
        const int col = n0 + wn * 64 + n * 16 + col16;
#pragma unroll
        for (int r = 0; r < 4; ++r) {
          const int row = m0 + wm * 64 + mi * 16 + quad * 4 + r;
          pb[(size_t)row * N + col] = f2bf(acc[mi][n][r]);
        }
      }
    }
    return;
  }
  if (mode == 5 && n0 >= 2048) {
    // fused vtrans: V section -> vt[(b*16+h)*64 + d][s], packed 8B stores.
#pragma unroll
    for (int mi = 0; mi < 4; ++mi) {
#pragma unroll
      for (int n = 0; n < 4; ++n) {
        const int col = n0 + wn * 64 + n * 16 + col16;
        const int hh = (col - 2048) >> 6, d = (col - 2048) & 63;
        const int row_base = m0 + wm * 64 + mi * 16 + quad * 4;
        const int bb = row_base >> 11, s = row_base & 2047;
        u16x4 o;
#pragma unroll
        for (int r = 0; r < 4; ++r) o[r] = f2bf(acc[mi][n][r]);
        *(u16x4*)(vt + (size_t)((bb * 16 + hh) * 64 + d) * SEQ + s) = o;
      }
    }
    return;
  }
  // Q pre-scale: fold softmax 1/sqrt(d)*log2(e) into the Q section of QKV.
  const float qscale = (mode == 5 && n0 < 1024) ? SCL : 1.0f;
  float bv[4];
  if (mode == 1) {
#pragma unroll
    for (int n = 0; n < 4; ++n) bv[n] = bias[n0 + wn * 64 + n * 16 + col16];
  }
#pragma unroll
  for (int mi = 0; mi < 4; ++mi) {
#pragma unroll
    for (int n = 0; n < 4; ++n) {
      const int col = n0 + wn * 64 + n * 16 + col16;
#pragma unroll
      for (int r = 0; r < 4; ++r) {
        const int row = m0 + wm * 64 + mi * 16 + quad * 4 + r;
        float v = acc[mi][n][r];
        if (mode == 1) v = fmaxf(v + bv[n], 0.0f);
        outB[(size_t)row * N + col] = f2bf(v * qscale);
      }
    }
  }
}

// ---------------- GEMM 64x128, BK=64, swizzled LDS, pipelined (wo GEMM) -----
// mode 2: +resid fp32 | 3: +bias+resid fp32
__global__ __launch_bounds__(256, 3) void gemm_bt64(
    const bf16u* __restrict__ A, const bf16u* __restrict__ Bt,
    int M, int N, int K,
    const float* __restrict__ bias, const float* __restrict__ resid,
    bf16u* __restrict__ outB, float* __restrict__ outF, int mode) {
  __shared__ bf16u As0[64 * 64], As1[64 * 64];
  __shared__ bf16u Bs0[128 * 64], Bs1[128 * 64];
  const int t = threadIdx.x;
  const int ln = t & 63;
  const int wv = t >> 6;
  const int col16 = ln & 15, quad = ln >> 4;

  const int nbx = gridDim.x;
  const int nwg = nbx * gridDim.y;          // 512 for our launches (%8==0)
  const int cpx = nwg >> 3;
  const int flat = blockIdx.y * nbx + blockIdx.x;
  const int swz = (flat & 7) * cpx + (flat >> 3);
  const int m0 = (swz / nbx) * 64, n0 = (swz % nbx) * 128;

  const bf16u* gA[2];
  const bf16u* gB[4];
#pragma unroll
  for (int j = 0; j < 2; ++j) {
    const int c = t + 256 * j, row = c >> 3, slot = (c & 7) ^ (row & 7);
    gA[j] = A + (size_t)(m0 + row) * K + slot * 8;
  }
#pragma unroll
  for (int j = 0; j < 4; ++j) {
    const int c = t + 256 * j, row = c >> 3, slot = (c & 7) ^ (row & 7);
    gB[j] = Bt + (size_t)(n0 + row) * K + slot * 8;
  }

  f32x4 acc[4][2] = {};

  auto stage = [&](bf16u* dA, bf16u* dB) {
#pragma unroll
    for (int j = 0; j < 2; ++j) {
      async_copy16(gA[j], dA + (size_t)(t + 256 * j) * 8);
      gA[j] += 64;
    }
#pragma unroll
    for (int j = 0; j < 4; ++j) {
      async_copy16(gB[j], dB + (size_t)(t + 256 * j) * 8);
      gB[j] += 64;
    }
  };
  auto compute = [&](const bf16u* sA, const bf16u* sB) {
    bf16x8 af[4][2], bfv[2][2];
#pragma unroll
    for (int mi = 0; mi < 4; ++mi) {
      const int row = mi * 16 + col16;
#pragma unroll
      for (int kc = 0; kc < 2; ++kc)
        af[mi][kc] = *(const bf16x8*)(sA + row * 64 + (((kc << 2) + quad) ^ (row & 7)) * 8);
    }
#pragma unroll
    for (int ni = 0; ni < 2; ++ni) {
      const int row = wv * 32 + ni * 16 + col16;
#pragma unroll
      for (int kc = 0; kc < 2; ++kc)
        bfv[ni][kc] = *(const bf16x8*)(sB + row * 64 + (((kc << 2) + quad) ^ (row & 7)) * 8);
    }
#pragma unroll
    for (int kc = 0; kc < 2; ++kc)
#pragma unroll
      for (int mi = 0; mi < 4; ++mi)
#pragma unroll
        for (int ni = 0; ni < 2; ++ni)
          acc[mi][ni] = __builtin_amdgcn_mfma_f32_16x16x32_bf16(af[mi][kc], bfv[ni][kc],
                                                                acc[mi][ni], 0, 0, 0);
  };

  const int niter = K >> 6;     // 16 (wo) — even
  stage(As0, Bs0);
  for (int k = 0; k < niter; k += 2) {
    stage(As1, Bs1);
    VM_WAIT(6);
    BARRIER();
    compute(As0, Bs0);
    BARRIER();
    if (k + 2 < niter) {
      stage(As0, Bs0);
      VM_WAIT(6);
    } else {
      VM_WAIT(0);
    }
    BARRIER();
    compute(As1, Bs1);
    BARRIER();
  }

#pragma unroll
  for (int mi = 0; mi < 4; ++mi) {
#pragma unroll
    for (int ni = 0; ni < 2; ++ni) {
      const int col = n0 + wv * 32 + ni * 16 + col16;
#pragma unroll
      for (int r = 0; r < 4; ++r) {
        const int row = m0 + mi * 16 + quad * 4 + r;
        float v = acc[mi][ni][r];
        if (mode == 1 || mode == 3) v += bias[col];
        if (mode == 1) v = fmaxf(v, 0.0f);
        if (mode >= 2) {
          outF[(size_t)row * N + col] = v + resid[(size_t)row * N + col];
        } else {
          outB[(size_t)row * N + col] = f2bf(v);
        }
      }
    }
  }
}

// ---------------- causal flash attention v6 + raw v_exp_f32 + setprio -------
// One 64-q-row strip per block, grid (bh=32, strips=32) heavy-first.
// Q pre-scaled by SCL at QKV epilogue. Softmax exp2 via v_exp_f32.
// Rotated software pipeline with RAW barriers + counted vmcnt.
// PV uses swapped MFMA operands -> O^T in C layout -> packed u16x4 stores.
#define PST 132   // pbuf row stride (elements): 128 keys + 4 pad
__global__ __launch_bounds__(256, 3) void attn_kernel(const bf16u* __restrict__ qkv,
                                                      const bf16u* __restrict__ vt,
                                                      bf16u* __restrict__ out) {
  __shared__ bf16u Ks[128 * 64];
  __shared__ bf16u Vts[2 * 64 * 64];
  __shared__ bf16u pbuf[4][16 * PST];
  __shared__ float lred[4][16];
  const int t = threadIdx.x;
  const int wv = t >> 6, ln = t & 63;
  const int col = ln & 15, quad = ln >> 4;
  const int bh = blockIdx.x, b = bh >> 4, h = bh & 15;
  const int strip = 31 - blockIdx.y;       // heavy blocks dispatch first
  const int q0 = strip * 64;
  const int qw = q0 + wv * 16;
  const int qmax = qw + 15;
  const int ntiles = (q0 >> 7) + 1;

  int krow[4], kslot[4], vrow[4], vsub[4], vslot[4];
  const bf16u *kl[4], *vl[4];
#pragma unroll
  for (int j = 0; j < 4; ++j) {
    const int c = t + 256 * j;
    krow[j] = c >> 3; kslot[j] = (c & 7) ^ (krow[j] & 7);
    const int rem = c & 511;
    vsub[j] = c >> 9; vrow[j] = rem >> 3; vslot[j] = (rem & 7) ^ (vrow[j] & 7);
    kl[j] = Ks + (size_t)c * 8;
    vl[j] = Vts + (size_t)c * 8;
  }

  auto stageK = [&](int kb) {
    const int kbase = kb * 128;
#pragma unroll
    for (int j = 0; j < 4; ++j)
      async_copy16(qkv + (size_t)(b * SEQ + kbase + krow[j]) * 3072 + 1024 + h * 64 + kslot[j] * 8, kl[j]);
  };
  auto stageV = [&](int kb) {
    const int kbase = kb * 128;
#pragma unroll
    for (int j = 0; j < 4; ++j)
      async_copy16(vt + (size_t)(bh * 64 + vrow[j]) * SEQ + kbase + vsub[j] * 64 + vslot[j] * 8, vl[j]);
  };

  bf16x8 qf0, qf1;
  {
    const size_t qoff = (size_t)(b * SEQ + qw + col) * 3072 + h * 64 + quad * 8;
    qf0 = *(const bf16x8*)(qkv + qoff);
    qf1 = *(const bf16x8*)(qkv + qoff + 32);
  }
  f32x4 po[4] = {};          // O^T accum: po[n] rows hd=n*16+quad*4+r, col q
  float ll[4] = {};          // per-lane softmax denominator partials

  stageK(0);
  stageV(0);
  VM_WAIT(4);                // K0 landed (+ Q regs); V0 stays in flight
  BARRIER();

  for (int kb = 0; kb < ntiles; ++kb) {
    const int kbase = kb * 128;
    if (kb < ntiles - 1) {
      // ---------- fully-unmasked 128-key tile ----------
      f32x4 sc[8];
      __builtin_amdgcn_s_setprio(1);
#pragma unroll
      for (int n = 0; n < 8; ++n) {
        const int kr = n * 16 + col;
        const bf16x8 k0 = *(const bf16x8*)(Ks + kr * 64 + (quad ^ (kr & 7)) * 8);
        const bf16x8 k1 = *(const bf16x8*)(Ks + kr * 64 + ((4 + quad) ^ (kr & 7)) * 8);
        f32x4 z = {};
        z = __builtin_amdgcn_mfma_f32_16x16x32_bf16(qf0, k0, z, 0, 0, 0);
        sc[n] = __builtin_amdgcn_mfma_f32_16x16x32_bf16(qf1, k1, z, 0, 0, 0);
      }
      __builtin_amdgcn_s_setprio(0);
#pragma unroll
      for (int r = 0; r < 4; ++r) {
#pragma unroll
        for (int n = 0; n < 8; ++n) {
          const float e = exp2_hw(sc[n][r]);
          ll[r] += e;
          pbuf[wv][(quad * 4 + r) * PST + n * 16 + col] = f2bf_hw(e);
        }
      }
    } else {
      // ---------- diagonal tile: mask + wave-uniform n-tile skip ----------
      f32x4 sc[8];
      bool act[8];
      __builtin_amdgcn_s_setprio(1);
#pragma unroll
      for (int n = 0; n < 8; ++n) {
        act[n] = (kbase + n * 16) <= qmax;
        if (act[n]) {
          const int kr = n * 16 + col;
          const bf16x8 k0 = *(const bf16x8*)(Ks + kr * 64 + (quad ^ (kr & 7)) * 8);
          const bf16x8 k1 = *(const bf16x8*)(Ks + kr * 64 + ((4 + quad) ^ (kr & 7)) * 8);
          f32x4 z = {};
          z = __builtin_amdgcn_mfma_f32_16x16x32_bf16(qf0, k0, z, 0, 0, 0);
          sc[n] = __builtin_amdgcn_mfma_f32_16x16x32_bf16(qf1, k1, z, 0, 0, 0);
        }
      }
      __builtin_amdgcn_s_setprio(0);
#pragma unroll
      for (int r = 0; r < 4; ++r) {
        const int q = qw + quad * 4 + r;
#pragma unroll
        for (int n = 0; n < 8; ++n) {
          float e = 0.0f;
          if (act[n]) {
            float v = sc[n][r];
            v = (kbase + n * 16 + col <= q) ? v : -1e30f;   // v_exp_f32 -> 0
            e = exp2_hw(v);
          }
          ll[r] += e;
          pbuf[wv][(quad * 4 + r) * PST + n * 16 + col] = f2bf_hw(e);
        }
      }
    }
    LGKM0();           // wave-local P writes done (drains Ks reads too)
    bf16x8 pa[4];
#pragma unroll
    for (int kc = 0; kc < 4; ++kc)
      pa[kc] = *(const bf16x8*)(&pbuf[wv][col * PST + kc * 32 + quad * 8]);
    VM_WAIT(0);        // V_kb landed
    BARRIER();         // all waves: Ks reads drained, Vts populated
    if (kb + 1 < ntiles) stageK(kb + 1);   // K latency hides under PV
    if (kb < ntiles - 1) {
      __builtin_amdgcn_s_setprio(1);
#pragma unroll
      for (int n = 0; n < 4; ++n) {
        const int vr = n * 16 + col;
#pragma unroll
        for (int kc = 0; kc < 4; ++kc) {
          const bf16x8 vfr = *(const bf16x8*)(Vts + (kc >> 1) * 4096 + vr * 64 +
                                              (((kc & 1) * 4 + quad) ^ (vr & 7)) * 8);
          // swapped operands: C = V^T * P^T = O^T (col=q, row=hd)
          po[n] = __builtin_amdgcn_mfma_f32_16x16x32_bf16(vfr, pa[kc], po[n], 0, 0, 0);
        }
      }
      __builtin_amdgcn_s_setprio(0);
    } else {
      __builtin_amdgcn_s_setprio(1);
#pragma unroll
      for (int n = 0; n < 4; ++n) {
        const int vr = n * 16 + col;
#pragma unroll
        for (int kc = 0; kc < 4; ++kc)
          if (kbase + kc * 32 <= qmax) {
            const bf16x8 vfr = *(const bf16x8*)(Vts + (kc >> 1) * 4096 + vr * 64 +
                                                (((kc & 1) * 4 + quad) ^ (vr & 7)) * 8);
            po[n] = __builtin_amdgcn_mfma_f32_16x16x32_bf16(vfr, pa[kc], po[n], 0, 0, 0);
          }
      }
      __builtin_amdgcn_s_setprio(0);
    }
    if (kb + 1 < ntiles) {
      LGKM0();         // own Vts reads drained
      BARRIER();       // all waves done reading Vts
      stageV(kb + 1);  // V latency hides under next QK^T+softmax
      VM_WAIT(4);      // K_{kb+1} landed (in-order retire); V in flight
      BARRIER();
    }
  }

  // reduce l across the 16 q-columns, broadcast via LDS, normalize, store O^T
#pragma unroll
  for (int m = 1; m < 16; m <<= 1)
#pragma unroll
    for (int r = 0; r < 4; ++r) ll[r] += __shfl_xor(ll[r], m, 64);
  if (col == 0) {
#pragma unroll
    for (int r = 0; r < 4; ++r) lred[wv][quad * 4 + r] = ll[r];
  }
  LGKM0();
  const float inv = 1.0f / lred[wv][col];
#pragma unroll
  for (int n = 0; n < 4; ++n) {
    u16x4 o;
#pragma unroll
    for (int r = 0; r < 4; ++r) o[r] = f2bf(po[n][r] * inv);
    *(u16x4*)(out + (size_t)(b * SEQ + qw + col) * DM + h * 64 + n * 16 + quad * 4) = o;
  }
}

// ---------------- launch ----------------
extern "C" void kernel_launch(void* const* d_in, const int* in_sizes, int n_in,
                              void* d_out, int out_size, void* d_ws, size_t ws_size,
                              hipStream_t stream) {
  const float* x   = (const float*)d_in[0];
  const float* wq  = (const float*)d_in[1];
  const float* wk  = (const float*)d_in[2];
  const float* wvv = (const float*)d_in[3];
  const float* wo  = (const float*)d_in[4];
  const float* w1  = (const float*)d_in[5];
  const float* b1  = (const float*)d_in[6];
  const float* w2  = (const float*)d_in[7];
  const float* b2  = (const float*)d_in[8];
  const float* g1  = (const float*)d_in[9];
  const float* be1 = (const float*)d_in[10];
  const float* g2  = (const float*)d_in[11];
  const float* be2 = (const float*)d_in[12];
  float* out = (float*)d_out;

  char* ws = (char*)d_ws;
  bf16u* wqkv_t = (bf16u*)(ws);              //  0 ..  6 MB  (3072 x 1024)
  bf16u* wo_t   = (bf16u*)(ws +  6291456);   //  6 ..  8 MB  (1024 x 1024)
  bf16u* w1_t   = (bf16u*)(ws +  8388608);   //  8 .. 16 MB  (4096 x 1024)
  bf16u* w2_t   = (bf16u*)(ws + 16777216);   // 16 .. 24 MB  (1024 x 4096)
  bf16u* lnbuf  = (bf16u*)(ws + 25165824);   // 24 .. 32 MB  (4096 x 1024) also attn out
  bf16u* qkv    = (bf16u*)(ws + 33554432);   // 32 .. 56 MB  (4096 x 3072)
  bf16u* vtb    = (bf16u*)(ws + 58720256);   // 56 .. 64 MB  (32 x 64 x 2048)
  bf16u* h1     = (bf16u*)(ws + 33554432);   // 32 .. 64 MB  (reuse: 4096 x 4096)
  bf16u* attn   = lnbuf;                     // ln1 dead after QKV GEMM
  // FFN2 split-K=2 partials (bf16, 8 MB each) over dead weight regions:
  bf16u* p01 = (bf16u*)(ws);                 //  0 .. 16 MB (dead wqkv/wo/w1)

  // fused preprocessing: LN1 + all weight transposes in ONE launch
  prep_kernel<<<16384, 256, 0, stream>>>(x, g1, be1, lnbuf,
                                         wq, wk, wvv, wo, wqkv_t,
                                         w1, w1_t, w2, w2_t);
  // QKV with fused V-transpose + Q pre-scale (mode 5). 128x128 tiles.
  gemm256<<<768, 256, 0, stream>>>(lnbuf, wqkv_t, 4096, 3072, 1024,
                                   nullptr, qkv, vtb, 5);
  attn_kernel<<<dim3(32, 32), 256, 0, stream>>>(qkv, vtb, attn);
  gemm_bt64<<<dim3(8, 64), 256, 0, stream>>>(attn, wo_t, 4096, 1024, 1024,
                                             nullptr, x, nullptr, out, 2);
  ln_kernel<<<4096, 256, 0, stream>>>(out, g2, be2, lnbuf);
  gemm256<<<1024, 256, 0, stream>>>(lnbuf, w1_t, 4096, 4096, 1024,
                                    b1, h1, nullptr, 1);
  // FFN2: split-K=2 -> 512 blocks = exactly 2/CU (LDS cap), K=2048/block;
  // bf16 partials to dead ws, combined with bias into out (attn@wo + x).
  gemm256<<<512, 256, 0, stream>>>(h1, w2_t, 4096, 1024, 4096,
                                   nullptr, p01, nullptr, 6);
  reduce2<<<2048, 256, 0, stream>>>(p01, b2, out);
}